// Round 8
// baseline (2537.368 us; speedup 1.0000x reference)
//
#include <hip/hip_runtime.h>
#include <hip/hip_bf16.h>
#include <float.h>

// LiDAR BEV pipeline (fp32 I/O):
//   voxelize -> conv3d(1->32)+BN+ReLU -> conv3d(32->64)+BN+ReLU -> conv3d(64->64)+BN+ReLU -> max over D
// R21: 516us (conv3 252, noise band 235-253). conv3 at 1.5x its 161us LDS-read floor;
//   capacity-pinned: weights (55KB streamed) + 6-slice at (78KB) fight for 160KB LDS.
// R22: WEIGHTS FROM L2, NOT LDS. Each wave reads the whole weight quarter per phase anyway
//   (per-lane 16B slices) -> per-lane global_load_dwordx4 from L2-resident wr2b/wr3b:
//   (1) LDS reads 126->72/phase (floor 161->92us), weights ride the parallel vmem pipe;
//   (2) no weight-DMA drains at barriers;
//   (3) LDS = at only (78,336B) -> 2 blocks/CU (launch_bounds(512,4), VGPR<=128) so one
//       block's barrier/transform stalls hide under the other's MFMAs.
//   conv2 same treatment (flat 6-slice at, ring dropped - occupancy > staging savings).
//   Tripwire: FETCH/WRITE inflation = spill (R20 signature) -> revert.

#define VOXEL 0.0625f
#define D_ 128
#define H_ 128
#define W_ 32
#define HW_ (H_*W_)      // 4096
#define DHW_ (D_*H_*W_)  // 524288
#define B_ 2
#define EPSV 1e-5f
#define OUTN_ (B_*64*HW_) // 524288
#define NBUCK 128         // stats buckets

typedef __hip_bfloat16 bf16;
typedef __attribute__((ext_vector_type(8))) short short8;   // 8 bf16
typedef __attribute__((ext_vector_type(4))) short short4v;  // 4 bf16
typedef __attribute__((ext_vector_type(4))) float f32x4;

// order-preserving float->uint key (ascending): neg -> ~bits, nonneg -> bits|signbit
__device__ inline unsigned fminkey(float f){
  unsigned b = __float_as_uint(f);
  return (b & 0x80000000u) ? ~b : (b | 0x80000000u);
}
__device__ inline float fminkey_inv(unsigned u){
  return (u & 0x80000000u) ? __uint_as_float(u & 0x7fffffffu) : __uint_as_float(~u);
}

// ---------------- init: minu + stats buckets ----------------

__global__ void init_kernel(unsigned* __restrict__ minu, float* __restrict__ stb){
  int i = blockIdx.x*blockDim.x + threadIdx.x;
  if (i < 8) minu[i] = 0xFFFFFFFFu;
  for (int k = i; k < 3*NBUCK*128; k += gridDim.x*blockDim.x) stb[k] = 0.f;
}

// ---------------- prep: zero g0 + minpart + all weight reorders (fused) ----------------

__global__ void prep_kernel(const float* __restrict__ pc, unsigned* __restrict__ minu,
                            float* __restrict__ g0,
                            const float* __restrict__ w1, float* __restrict__ wr1,
                            const float* __restrict__ w2, float* __restrict__ wr2,
                            bf16* __restrict__ wr2b,
                            const float* __restrict__ w3, bf16* __restrict__ wr3b,
                            int N){
  const int bid = blockIdx.x;
  const int tid = threadIdx.x;
  if (bid < 4096){                       // zero occupancy grid (1,048,576 floats)
    g0[(size_t)bid*256 + tid] = 0.f;
    return;
  }
  if (bid < 4288){                       // minpart: 192 = 6 rows x 32 x-parts
    int p = bid - 4096;
    int row = p >> 5, xp = p & 31;
    const float* base = pc + (size_t)row * N;
    float m = FLT_MAX;
    for (int j = xp*256 + tid; j < N; j += 8192){
      float v = base[j];
      if (v != v) v = 0.f;               // NaN -> 0, matching reference
      m = fminf(m, v);
    }
    for (int off = 32; off > 0; off >>= 1)
      m = fminf(m, __shfl_xor(m, off, 64));
    __shared__ float red[4];
    int wave = tid >> 6;
    if ((tid & 63) == 0) red[wave] = m;
    __syncthreads();
    if (tid == 0){
      float r = fminf(fminf(red[0], red[1]), fminf(red[2], red[3]));
      atomicMin(&minu[row], fminkey(r));
    }
    return;
  }
  if (bid < 4292){                       // w1 (32,1,27) -> [27tap][32o] fp32
    int idx = (bid - 4288)*256 + tid;
    if (idx < 864){
      int o = idx / 27, k = idx - o*27;
      wr1[k*32 + o] = w1[idx];
    }
    return;
  }
  if (bid < 4508){                       // w2 fp32 [i*27+k][64o] (fallback path)
    int idx = (bid - 4292)*256 + tid;
    if (idx < 55296){
      int o = idx / (32*27);
      int rem = idx - o*(32*27);
      int i = rem / 27, k = rem - i*27;
      wr2[(i*27 + k)*64 + o] = w2[idx];
    }
    return;
  }
  if (bid < 4724){                       // w2 -> [oh][tap][iq][o'][j] bf16 quarters
    int idx = (bid - 4508)*256 + tid;
    if (idx < 55296){
      int o = idx / (32*27);
      int rem = idx - o*(32*27);
      int i = rem / 27, tap = rem - i*27;
      int oh = o >> 5, op = o & 31;
      int iq = i >> 3, j = i & 7;
      wr2b[(((((size_t)oh*27 + tap)*4 + iq)*32 + op) << 3) | j] = __float2bfloat16(w2[idx]);
    }
    return;
  }
  {                                      // w3 -> [oh][ic][tap][iq][o'][j] bf16 quarters
    int idx = (bid - 4724)*256 + tid;
    if (idx < 110592){
      int o = idx / (64*27);
      int rem = idx - o*(64*27);
      int i = rem / 27, tap = rem - i*27;
      int oh = o >> 5, op = o & 31;
      int ic = i >> 5, iq = (i & 31) >> 3, j = i & 7;
      wr3b[(((((size_t)(oh*2 + ic)*27 + tap)*4 + iq)*32 + op) << 3) | j] = __float2bfloat16(w3[idx]);
    }
    return;
  }
}

// ---------------- voxelize scatter ----------------

__global__ void scatter_kernel(const float* __restrict__ pc, const unsigned* __restrict__ minu,
                               float* __restrict__ grid, int N){
  int idx = blockIdx.x*blockDim.x + threadIdx.x;
  if (idx >= B_*N) return;
  int b = idx / N, n = idx - b*N;
  float x = pc[((size_t)b*3 + 0)*N + n];
  float y = pc[((size_t)b*3 + 1)*N + n];
  float z = pc[((size_t)b*3 + 2)*N + n];
  if (x != x) x = 0.f;
  if (y != y) y = 0.f;
  if (z != z) z = 0.f;
  int ix = (int)floorf((x - fminkey_inv(minu[b*3+0])) / VOXEL);
  int iy = (int)floorf((y - fminkey_inv(minu[b*3+1])) / VOXEL);
  int iz = (int)floorf((z - fminkey_inv(minu[b*3+2])) / VOXEL);
  ix = min(max(ix, 0), D_-1);
  iy = min(max(iy, 0), H_-1);
  iz = min(max(iz, 0), W_-1);
  grid[(size_t)b*DHW_ + (size_t)ix*HW_ + iy*W_ + iz] = 1.0f;
}

// ---------------- fp32 conv inner (conv1-class kernels) ----------------

template<int HT, int OPT, int COUT>
__device__ inline void conv_inner(float (*xs)[HT+2][34], float (*wsm)[COUT],
                                  int w, int og, float (*acc)[OPT]){
  #pragma unroll
  for (int kd = 0; kd < 3; ++kd){
    float xr[HT+2][3];
    #pragma unroll
    for (int r = 0; r < HT+2; ++r)
      #pragma unroll
      for (int c = 0; c < 3; ++c)
        xr[r][c] = xs[kd][r][w + c];
    #pragma unroll
    for (int kh = 0; kh < 3; ++kh)
      #pragma unroll
      for (int kw = 0; kw < 3; ++kw){
        const float* wp = &wsm[kd*9 + kh*3 + kw][og*OPT];
        float wv[OPT];
        #pragma unroll
        for (int oo = 0; oo < OPT; ++oo) wv[oo] = wp[oo];
        #pragma unroll
        for (int h = 0; h < HT; ++h){
          float xv = xr[h + kh][kw];
          #pragma unroll
          for (int oo = 0; oo < OPT; ++oo)
            acc[h][oo] = fmaf(xv, wv[oo], acc[h][oo]);
        }
      }
  }
}

// ---------------- conv1 BN stats only (fallback path) ----------------

__global__ __launch_bounds__(256)
void convstats_kernel(const float* __restrict__ X, const float* __restrict__ WR,
                      const float* __restrict__ bias, float* __restrict__ stats){
  const int tid = threadIdx.x;
  const int w   = tid & 31;
  const int og  = tid >> 5;
  const int h0  = blockIdx.x * 8;
  const int d   = blockIdx.y;
  const int b   = blockIdx.z;
  const int bucket = d & (NBUCK - 1);

  __shared__ float xs[3][10][34];
  __shared__ float wsm[27][32];

  float acc[8][4];
  #pragma unroll
  for (int h = 0; h < 8; ++h)
    #pragma unroll
    for (int oo = 0; oo < 4; ++oo) acc[h][oo] = 0.f;

  for (int e = tid; e < 27*32; e += 256)
    ((float*)wsm)[e] = WR[e];
  for (int e = tid; e < 960; e += 256){
    int ds = e / 320; int rem = e - ds*320; int r = rem >> 5; int ww = rem & 31;
    int dd = d + ds - 1, hh = h0 + r - 1;
    float v = 0.f;
    if (dd >= 0 && dd < D_ && hh >= 0 && hh < H_)
      v = X[((size_t)b*D_ + dd)*HW_ + hh*W_ + ww];
    xs[ds][r][ww + 1] = v;
  }
  if (tid < 30){ int ds = tid/10, r = tid - ds*10; xs[ds][r][0] = 0.f; xs[ds][r][33] = 0.f; }
  __syncthreads();
  conv_inner<8, 4, 32>(xs, wsm, w, og, acc);

  #pragma unroll
  for (int oo = 0; oo < 4; ++oo){
    int o = og*4 + oo;
    float bo = bias[o];
    float s1 = 0.f, s2 = 0.f;
    #pragma unroll
    for (int h = 0; h < 8; ++h){
      float y = acc[h][oo] + bo;
      s1 += y;
      s2 = fmaf(y, y, s2);
    }
    for (int m = 16; m > 0; m >>= 1){
      s1 += __shfl_xor(s1, m, 32);
      s2 += __shfl_xor(s2, m, 32);
    }
    if (w == 0){
      atomicAdd(&stats[bucket*128 + o], s1);
      atomicAdd(&stats[bucket*128 + 32 + o], s2);
    }
  }
}

// ---------------- conv1 -> RAW x1 channel-last bf16 [b][d][h][w][32] + BN1 stats ----------------

__global__ __launch_bounds__(256)
void conv1act_kernel(const float* __restrict__ X, const float* __restrict__ WR,
                     const float* __restrict__ bias, bf16* __restrict__ X1,
                     float* __restrict__ stats){
  const int tid = threadIdx.x;
  const int w   = tid & 31;
  const int og  = tid >> 5;
  const int h0  = blockIdx.x * 8;
  const int d   = blockIdx.y;
  const int b   = blockIdx.z;
  const int bucket = d & (NBUCK - 1);

  __shared__ float xs[3][10][34];
  __shared__ float wsm[27][32];

  float acc[8][4];
  #pragma unroll
  for (int h = 0; h < 8; ++h)
    #pragma unroll
    for (int oo = 0; oo < 4; ++oo) acc[h][oo] = 0.f;

  for (int e = tid; e < 27*32; e += 256)
    ((float*)wsm)[e] = WR[e];
  for (int e = tid; e < 960; e += 256){
    int ds = e / 320; int rem = e - ds*320; int r = rem >> 5; int ww = rem & 31;
    int dd = d + ds - 1, hh = h0 + r - 1;
    float v = 0.f;
    if (dd >= 0 && dd < D_ && hh >= 0 && hh < H_)
      v = X[((size_t)b*D_ + dd)*HW_ + hh*W_ + ww];
    xs[ds][r][ww + 1] = v;
  }
  if (tid < 30){ int ds = tid/10, r = tid - ds*10; xs[ds][r][0] = 0.f; xs[ds][r][33] = 0.f; }
  __syncthreads();
  conv_inner<8, 4, 32>(xs, wsm, w, og, acc);

  float bo[4], psum[4], psq[4];
  #pragma unroll
  for (int oo = 0; oo < 4; ++oo){
    bo[oo] = bias[og*4 + oo]; psum[oo] = 0.f; psq[oo] = 0.f;
  }
  #pragma unroll
  for (int h = 0; h < 8; ++h){
    bf16 row[4];
    #pragma unroll
    for (int oo = 0; oo < 4; ++oo){
      float y = acc[h][oo] + bo[oo];
      row[oo] = __float2bfloat16(y);
      psum[oo] += y;
      psq[oo]  = fmaf(y, y, psq[oo]);
    }
    *(short4v*)&X1[((((size_t)b*D_ + d)*H_ + (h0 + h))*W_ + w)*32 + og*4] = *(short4v*)row;
  }
  #pragma unroll
  for (int oo = 0; oo < 4; ++oo){
    float s1 = psum[oo], s2 = psq[oo];
    for (int m = 16; m > 0; m >>= 1){
      s1 += __shfl_xor(s1, m, 32);
      s2 += __shfl_xor(s2, m, 32);
    }
    if (w == 0){
      int o = og*4 + oo;
      atomicAdd(&stats[bucket*128 + o], s1);
      atomicAdd(&stats[bucket*128 + 32 + o], s2);
    }
  }
}

// ---------------- fused12 (fp32 fallback path, writes raw x2 + BN2 stats) ----------------

__global__ __launch_bounds__(256)
void fused12_kernel(const float* __restrict__ G0, const float* __restrict__ WR1,
                    const float* __restrict__ B1, const float* __restrict__ SS1,
                    const float* __restrict__ WR2, const float* __restrict__ B2,
                    bf16* __restrict__ X2, float* __restrict__ stats){
  const int tid = threadIdx.x;
  const int w   = tid & 31;
  const int og  = tid >> 5;
  const int h0  = blockIdx.x * 8;
  const int d   = blockIdx.y;
  const int b   = blockIdx.z;
  const int bucket = d & (NBUCK - 1);

  __shared__ float gs[5][12][34];
  __shared__ float w1s[32][27];
  __shared__ float xs[3][10][34];
  __shared__ float wsm[27][64];

  for (int e = tid; e < 5*12*34; e += 256){
    int ds = e / 408; int rem = e - ds*408; int r = rem / 34; int c = rem - r*34;
    int dd = d - 2 + ds, hh = h0 - 2 + r, ww = c - 1;
    float v = 0.f;
    if (c >= 1 && c <= 32 && dd >= 0 && dd < D_ && hh >= 0 && hh < H_)
      v = G0[((size_t)b*D_ + dd)*HW_ + hh*W_ + ww];
    gs[ds][r][c] = v;
  }
  for (int e = tid; e < 864; e += 256){
    int i = e/27, k = e - 27*i;
    w1s[i][k] = WR1[k*32 + i];
  }

  float acc[8][8];
  #pragma unroll
  for (int h = 0; h < 8; ++h)
    #pragma unroll
    for (int oo = 0; oo < 8; ++oo) acc[h][oo] = 0.f;

  for (int i = 0; i < 32; ++i){
    __syncthreads();
    float a1 = SS1[i];
    float f1 = fmaf(a1, B1[i], SS1[32 + i]);
    for (int e = tid; e < 1020; e += 256){
      int ds = e / 340; int rem = e - ds*340; int r = rem / 34; int c = rem - r*34;
      float v = 0.f;
      int dd = d - 1 + ds, hh = h0 - 1 + r;
      if (c >= 1 && c <= 32 && dd >= 0 && dd < D_ && hh >= 0 && hh < H_){
        float s = 0.f;
        #pragma unroll
        for (int kd = 0; kd < 3; ++kd)
          #pragma unroll
          for (int kh = 0; kh < 3; ++kh)
            #pragma unroll
            for (int kw = 0; kw < 3; ++kw)
              s = fmaf(gs[ds+kd][r+kh][c-1+kw], w1s[i][kd*9+kh*3+kw], s);
        v = fmaxf(fmaf(a1, s, f1), 0.f);
      }
      xs[ds][r][c] = v;
    }
    for (int e = tid; e < 27*64; e += 256)
      ((float*)wsm)[e] = WR2[i*27*64 + e];
    __syncthreads();
    conv_inner<8, 8, 64>(xs, wsm, w, og, acc);
  }

  float bo[8], psum[8], psq[8];
  #pragma unroll
  for (int oo = 0; oo < 8; ++oo){ bo[oo] = B2[og*8 + oo]; psum[oo] = 0.f; psq[oo] = 0.f; }
  #pragma unroll
  for (int h = 0; h < 8; ++h){
    bf16 row[8];
    #pragma unroll
    for (int oo = 0; oo < 8; ++oo){
      float y = acc[h][oo] + bo[oo];
      row[oo] = __float2bfloat16(y);
      psum[oo] += y;
      psq[oo]  = fmaf(y, y, psq[oo]);
    }
    *(short8*)&X2[((((size_t)b*D_ + d)*H_ + (h0 + h))*W_ + w)*64 + og*8] = *(short8*)row;
  }
  #pragma unroll
  for (int oo = 0; oo < 8; ++oo){
    float s1 = psum[oo], s2 = psq[oo];
    for (int m = 16; m > 0; m >>= 1){
      s1 += __shfl_xor(s1, m, 32);
      s2 += __shfl_xor(s2, m, 32);
    }
    if (w == 0){
      atomicAdd(&stats[bucket*128 + og*8 + oo], s1);
      atomicAdd(&stats[bucket*128 + 64 + og*8 + oo], s2);
    }
  }
}

// ---------------- conv2 MFMA (512 thr, o-halved, 2d/wave, kd-dedup, L2 weights) ----------------
// R22: weights read per-lane from L2 (wr2b quarter, [oh][tap][iq][o'][j]); LDS = at only
// (78,336B) -> 2 blocks/CU. Per (kh,kw): bfa[4][2] LDS reads shared across kd; afw global.

template<int DCHUNK>
__global__ __launch_bounds__(512, 4)
void conv2mfma_kernel(const bf16* __restrict__ X1, const bf16* __restrict__ WB,
                      const float* __restrict__ SS1, const float* __restrict__ B2,
                      bf16* __restrict__ X2, float* __restrict__ stats){
  const int tid  = threadIdx.x;
  const int lane = tid & 63;
  const int wv   = tid >> 6;        // 0..7
  const int hrow = wv & 3;
  const int dsub = wv >> 2;
  const int l15  = lane & 15;
  const int quad = lane >> 4;
  const int hb   = blockIdx.x & 31;
  const int oh   = blockIdx.x >> 5;       // o half
  const int h0   = hb * 4;
  const int d0   = blockIdx.y * DCHUNK;
  const int b    = blockIdx.z;
  const int bucket = (hb | ((int)blockIdx.y << 5) | (oh << 6)) & (NBUCK - 1);

  __shared__ __align__(16) bf16 at[6][6][34][32];     // 78,336 B (6 d-slices) — ALL the LDS

  // per-lane weight base in L2: element ((tap*4+quad)*32 + mt*16 + l15)*8
  const bf16* Wl = WB + (size_t)oh*27648 + ((size_t)(quad*32 + l15) << 3);

  // zero the w-halo pad columns (never rewritten)
  for (int e = tid; e < 6*6*2*32; e += 512){
    int ch = e & 31; int side = (e >> 5) & 1; int r = (e >> 6) % 6; int sl = (e >> 6) / 6;
    at[sl][r][side ? 33 : 0][ch] = __float2bfloat16(0.f);
  }

  const int wlane = lane >> 2;
  const int swz   = (((lane >> 2) + 1) >> 1) & 3;
  const int gch   = (lane & 3) ^ swz;

  float sa[8], sb[8];
  #pragma unroll
  for (int j = 0; j < 8; ++j){
    sa[j] = SS1[gch*8 + j];
    sb[j] = SS1[32 + gch*8 + j];
  }

  float br[2][4], psum[2][4], psq[2][4];
  #pragma unroll
  for (int mt = 0; mt < 2; ++mt)
    #pragma unroll
    for (int rg = 0; rg < 4; ++rg){
      br[mt][rg] = B2[oh*32 + mt*16 + quad*4 + rg];
      psum[mt][rg] = 0.f; psq[mt][rg] = 0.f;
    }

  int rsl[5], rr[5];
  #pragma unroll
  for (int jj = 0; jj < 5; ++jj){
    int j = wv + jj*8;
    rsl[jj] = j / 6; rr[jj] = j - rsl[jj]*6;
  }

  short8 xr[10] = {};
  bool rok[5] = {false, false, false, false, false};

  auto stage_load = [&](int dbase){
    #pragma unroll
    for (int jj = 0; jj < 5; ++jj){
      int j = wv + jj*8;                          // wave-uniform
      int dd = dbase - 1 + rsl[jj], hh = h0 - 1 + rr[jj];
      rok[jj] = (j < 36) && dd >= 0 && dd < D_ && hh >= 0 && hh < H_;
      if (rok[jj]){
        const bf16* rowp = X1 + (((size_t)b*D_ + dd)*H_ + hh)*W_*32 + gch*8;
        xr[jj*2+0] = *(const short8*)(rowp + (size_t)wlane*32);
        xr[jj*2+1] = *(const short8*)(rowp + (size_t)(wlane + 16)*32);
      }
    }
  };

  auto stage_flush = [&](){
    // in-place BN1+ReLU transform (pre-barrier)
    #pragma unroll
    for (int jj = 0; jj < 5; ++jj)
      #pragma unroll
      for (int half = 0; half < 2; ++half){
        short8 v = xr[jj*2+half];
        short8 o8 = (short8){0,0,0,0,0,0,0,0};
        if (rok[jj]){
          bf16* pv = (bf16*)&v; bf16* po = (bf16*)&o8;
          #pragma unroll
          for (int j = 0; j < 8; ++j)
            po[j] = __float2bfloat16(fmaxf(fmaf(sa[j], __bfloat162float(pv[j]), sb[j]), 0.f));
        }
        xr[jj*2+half] = o8;
      }
    __syncthreads();                 // all waves done reading at
    #pragma unroll
    for (int jj = 0; jj < 5; ++jj)
      if (wv + jj*8 < 36)            // wave-uniform guard
        #pragma unroll
        for (int half = 0; half < 2; ++half)
          *(short8*)(&at[rsl[jj]][rr[jj]][1 + half*16][0] + (size_t)lane*8) = xr[jj*2+half];
    __syncthreads();                 // publish act writes
  };

  stage_load(d0);

  f32x4 acc[2][2][2];               // [dd][mt][nt]
  #pragma unroll 1
  for (int g = 0; g < DCHUNK/4; ++g){
    const int dbase = d0 + 4*g;
    #pragma unroll
    for (int dd = 0; dd < 2; ++dd)
      #pragma unroll
      for (int mt = 0; mt < 2; ++mt)
        #pragma unroll
        for (int nt = 0; nt < 2; ++nt)
          acc[dd][mt][nt] = (f32x4){0.f, 0.f, 0.f, 0.f};

    stage_flush();
    if (g + 1 < DCHUNK/4) stage_load(dbase + 4);   // in flight across MFMA phase

    #pragma unroll
    for (int kh = 0; kh < 3; ++kh)
      #pragma unroll
      for (int kw = 0; kw < 3; ++kw){
        short8 bfa[4][2];
        #pragma unroll
        for (int sl = 0; sl < 4; ++sl)
          #pragma unroll
          for (int nt = 0; nt < 2; ++nt){
            int W = nt*16 + l15 + kw;
            int pq = (quad ^ ((W >> 1) & 3)) * 8;
            bfa[sl][nt] = *(const short8*)&at[2*dsub + sl][hrow + kh][W][pq];
          }
        #pragma unroll
        for (int kd = 0; kd < 3; ++kd){
          const int tap = (kd*3 + kh)*3 + kw;
          short8 afw[2];
          #pragma unroll
          for (int mt = 0; mt < 2; ++mt)
            afw[mt] = *(const short8*)(Wl + tap*1024 + mt*128);   // L2 read
          #pragma unroll
          for (int dd = 0; dd < 2; ++dd)
            #pragma unroll
            for (int mt = 0; mt < 2; ++mt)
              #pragma unroll
              for (int nt = 0; nt < 2; ++nt)
                acc[dd][mt][nt] = __builtin_amdgcn_mfma_f32_16x16x32_bf16(
                    afw[mt], bfa[dd + kd][nt], acc[dd][mt][nt], 0, 0, 0);
        }
      }

    // epilogue: this wave's 2 d rows
    #pragma unroll
    for (int dd = 0; dd < 2; ++dd){
      const size_t rowbase = (((size_t)b*D_ + (dbase + 2*dsub + dd))*H_ + (h0 + hrow))*W_;
      #pragma unroll
      for (int nt = 0; nt < 2; ++nt){
        const size_t pix = (rowbase + nt*16 + l15)*64;
        #pragma unroll
        for (int mt = 0; mt < 2; ++mt){
          bf16 row[4];
          #pragma unroll
          for (int rg = 0; rg < 4; ++rg){
            float y = acc[dd][mt][nt][rg] + br[mt][rg];
            psum[mt][rg] += y;
            psq[mt][rg]  = fmaf(y, y, psq[mt][rg]);
            row[rg] = __float2bfloat16(y);
          }
          *(short4v*)&X2[pix + oh*32 + mt*16 + quad*4] = *(short4v*)row;
        }
      }
    }
  }

  // BN2 stats
  #pragma unroll
  for (int mt = 0; mt < 2; ++mt)
    #pragma unroll
    for (int rg = 0; rg < 4; ++rg){
      float s1 = psum[mt][rg], s2 = psq[mt][rg];
      #pragma unroll
      for (int m = 1; m < 16; m <<= 1){
        s1 += __shfl_xor(s1, m, 64);
        s2 += __shfl_xor(s2, m, 64);
      }
      if (l15 == 0){
        int o = oh*32 + mt*16 + quad*4 + rg;
        atomicAdd(&stats[bucket*128 + o], s1);
        atomicAdd(&stats[bucket*128 + 64 + o], s2);
      }
    }
}

// ---------------- conv3 MFMA (512 thr, o-halved, M=64/wave, L2 weights) ----------------
// R22: bfr read per-lane from L2 (wr3b quarter); LDS = at only (78,336B) -> 2 blocks/CU.
// Per (kh,kw): af[4][2] LDS reads shared across kd (72 LDS reads/phase, was 126).

template<int DCHUNK>
__global__ __launch_bounds__(512, 4)
void conv3mfma_kernel(const bf16* __restrict__ X, const bf16* __restrict__ WB,
                      const float* __restrict__ SS2, const float* __restrict__ bias,
                      float* __restrict__ stats,
                      bf16* __restrict__ minp, bf16* __restrict__ maxp){
  const int tid  = threadIdx.x;
  const int lane = tid & 63;
  const int wv   = tid >> 6;
  const int hrow = wv & 3;
  const int dsub = wv >> 2;
  const int l15  = lane & 15;
  const int quad = lane >> 4;
  const int hb   = blockIdx.x & 31;
  const int oh   = blockIdx.x >> 5;       // o half
  const int h0   = hb * 4;
  const int d0   = blockIdx.y * DCHUNK;
  const int b    = blockIdx.z;
  const int bucket = (hb | ((int)blockIdx.y << 5) | (oh << 6)) & (NBUCK - 1);

  __shared__ __align__(16) bf16 at[6][6][34][32];        // 78,336 B — ALL the LDS

  // per-lane weight bases in L2 for both ic quarters
  const bf16* Wl0 = WB + (size_t)(oh*2)*27648 + ((size_t)(quad*32 + l15) << 3);
  const bf16* Wl1 = Wl0 + 27648;

  // zero the w-halo pad columns (never rewritten)
  for (int e = tid; e < 6*6*2*32; e += 512){
    int ch = e & 31; int side = (e >> 5) & 1; int r = (e >> 6) % 6; int sl = (e >> 6) / 6;
    at[sl][r][side ? 33 : 0][ch] = __float2bfloat16(0.f);
  }

  const int wlane = lane >> 2;
  const int swz   = (((lane >> 2) + 1) >> 1) & 3;
  const int gch   = (lane & 3) ^ swz;

  // BN2 scale/shift for this lane's staged channels, both ic halves (ic literal at use sites)
  float sa[2][8], sb[2][8];
  #pragma unroll
  for (int ic = 0; ic < 2; ++ic)
    #pragma unroll
    for (int j = 0; j < 8; ++j){
      sa[ic][j] = SS2[ic*32 + gch*8 + j];
      sb[ic][j] = SS2[64 + ic*32 + gch*8 + j];
    }

  f32x4 acc[4][2];                  // [mh][nt], mh = (mhh<<1)|wh
  float mmx[2][2][4], mmn[2][2][4]; // [wh][nt][rg] (mhh folds into the d-reduction)
  float brg[2];
  #pragma unroll
  for (int nt = 0; nt < 2; ++nt) brg[nt] = bias[oh*32 + nt*16 + l15];
  #pragma unroll
  for (int wh = 0; wh < 2; ++wh)
    #pragma unroll
    for (int nt = 0; nt < 2; ++nt)
      #pragma unroll
      for (int rg = 0; rg < 4; ++rg){ mmx[wh][nt][rg] = -FLT_MAX; mmn[wh][nt][rg] = FLT_MAX; }
  float psum[2] = {0.f,0.f}, psq[2] = {0.f,0.f};

  // 36 rows (6 slices x 6 h-rows); 5 slots/wave (waves 0..3 get 5, 4..7 get 4)
  int rsl[5], rr[5];
  #pragma unroll
  for (int jj = 0; jj < 5; ++jj){
    int j = wv + jj*8;
    rsl[jj] = j / 6; rr[jj] = j - rsl[jj]*6;
  }

  short8 xr[10] = {};
  bool rok[5] = {false, false, false, false, false};

  auto stage_load = [&](int dbase, int ic){
    #pragma unroll
    for (int jj = 0; jj < 5; ++jj){
      int j = wv + jj*8;                          // wave-uniform
      int dd = dbase - 1 + rsl[jj], hh = h0 - 1 + rr[jj];
      rok[jj] = (j < 36) && dd >= 0 && dd < D_ && hh >= 0 && hh < H_;
      if (rok[jj]){
        const bf16* rowp = X + (((size_t)b*D_ + dd)*H_ + hh)*W_*64 + ic*32 + gch*8;
        xr[jj*2+0] = *(const short8*)(rowp + (size_t)wlane*64);
        xr[jj*2+1] = *(const short8*)(rowp + (size_t)(wlane + 16)*64);
      }
    }
  };

  auto stage_flush = [&](int ic){
    // in-place BN2+ReLU transform (pre-barrier: overlaps other waves' MFMAs)
    #pragma unroll
    for (int jj = 0; jj < 5; ++jj)
      #pragma unroll
      for (int half = 0; half < 2; ++half){
        short8 v = xr[jj*2+half];
        short8 o8 = (short8){0,0,0,0,0,0,0,0};
        if (rok[jj]){
          bf16* pv = (bf16*)&v;
          bf16* po = (bf16*)&o8;
          #pragma unroll
          for (int j = 0; j < 8; ++j)
            po[j] = __float2bfloat16(fmaxf(fmaf(sa[ic][j], __bfloat162float(pv[j]), sb[ic][j]), 0.f));
        }
        xr[jj*2+half] = o8;
      }
    __syncthreads();                 // all waves done reading at of prev stage
    #pragma unroll
    for (int jj = 0; jj < 5; ++jj)
      if (wv + jj*8 < 36)            // wave-uniform guard
        #pragma unroll
        for (int half = 0; half < 2; ++half)
          *(short8*)(&at[rsl[jj]][rr[jj]][1 + half*16][0] + (size_t)lane*8) = xr[jj*2+half];
    __syncthreads();                 // publish act writes
  };

  auto do_mfma = [&](const bf16* Wl){
    #pragma unroll
    for (int kh = 0; kh < 3; ++kh)
      #pragma unroll
      for (int kw = 0; kw < 3; ++kw){
        // 8 act vectors: 4 d-slices x 2 w-halves, reused across kd (d-overlap dedup)
        short8 af[4][2];
        #pragma unroll
        for (int sl = 0; sl < 4; ++sl)
          #pragma unroll
          for (int wh = 0; wh < 2; ++wh){
            int W = wh*16 + l15 + kw;
            int pq = (quad ^ ((W >> 1) & 3)) * 8;
            af[sl][wh] = *(const short8*)&at[2*dsub + sl][hrow + kh][W][pq];
          }
        #pragma unroll
        for (int kd = 0; kd < 3; ++kd){
          const int tap = (kd*3 + kh)*3 + kw;
          short8 bfr[2];
          #pragma unroll
          for (int nt = 0; nt < 2; ++nt)
            bfr[nt] = *(const short8*)(Wl + tap*1024 + nt*128);   // L2 read
          #pragma unroll
          for (int mh = 0; mh < 4; ++mh)
            #pragma unroll
            for (int nt = 0; nt < 2; ++nt)
              acc[mh][nt] = __builtin_amdgcn_mfma_f32_16x16x32_bf16(
                  af[(mh >> 1) + kd][mh & 1], bfr[nt], acc[mh][nt], 0, 0, 0);
        }
      }
  };

  // prologue: acts for group 0 ic=0
  stage_load(d0, 0);

  #pragma unroll 1
  for (int g = 0; g < DCHUNK/4; ++g){
    const int dbase = d0 + 4*g;
    #pragma unroll
    for (int mh = 0; mh < 4; ++mh)
      #pragma unroll
      for (int nt = 0; nt < 2; ++nt)
        acc[mh][nt] = (f32x4){0.f, 0.f, 0.f, 0.f};

    // ---- ic = 0 phase ----
    stage_flush(0);
    stage_load(dbase, 1);            // ic1 acts in flight across MFMA
    do_mfma(Wl0);

    // ---- ic = 1 phase ----
    stage_flush(1);
    if (g + 1 < DCHUNK/4) stage_load(dbase + 4, 0);
    do_mfma(Wl1);

    // epilogue: accumulate stats + min/max (mhh folds into d-reduction)
    #pragma unroll
    for (int mh = 0; mh < 4; ++mh){
      const int wh = mh & 1;
      #pragma unroll
      for (int nt = 0; nt < 2; ++nt)
        #pragma unroll
        for (int rg = 0; rg < 4; ++rg){
          float y = acc[mh][nt][rg] + brg[nt];
          psum[nt] += y;
          psq[nt]  = fmaf(y, y, psq[nt]);
          mmx[wh][nt][rg] = fmaxf(mmx[wh][nt][rg], y);
          mmn[wh][nt][rg] = fminf(mmn[wh][nt][rg], y);
        }
    }
  }

  // BN3 stats: lanes {l15, +16, +32, +48} share o = oh*32 + nt*16 + l15
  #pragma unroll
  for (int nt = 0; nt < 2; ++nt){
    float s1 = psum[nt], s2 = psq[nt];
    s1 += __shfl_xor(s1, 16, 64);  s2 += __shfl_xor(s2, 16, 64);
    s1 += __shfl_xor(s1, 32, 64);  s2 += __shfl_xor(s2, 32, 64);
    if (quad == 0){
      int o = oh*32 + nt*16 + l15;
      atomicAdd(&stats[bucket*128 + o], s1);
      atomicAdd(&stats[bucket*128 + 64 + o], s2);
    }
  }

  const size_t slab_off = (size_t)((int)blockIdx.y*2 + dsub) * OUTN_;
  const int h = h0 + hrow;
  #pragma unroll
  for (int wh = 0; wh < 2; ++wh)
    #pragma unroll
    for (int nt = 0; nt < 2; ++nt){
      int o = oh*32 + nt*16 + l15;
      #pragma unroll
      for (int rg = 0; rg < 4; ++rg){
        int w = wh*16 + quad*4 + rg;
        size_t idx = slab_off + ((size_t)(b*64 + o))*HW_ + h*W_ + w;
        maxp[idx] = __float2bfloat16(mmx[wh][nt][rg]);
        minp[idx] = __float2bfloat16(mmn[wh][nt][rg]);
      }
    }
}

// ---------------- final: reduce slabs, apply BN3+ReLU via monotonicity ----------------

__global__ void bevreduce_kernel(const bf16* __restrict__ minp, const bf16* __restrict__ maxp,
                                 const float* __restrict__ ss, float* __restrict__ out, int nslab){
  int j = blockIdx.x*blockDim.x + threadIdx.x;
  if (j >= OUTN_) return;
  int o = (j >> 12) & 63;
  float mx = -FLT_MAX, mn = FLT_MAX;
  for (int s = 0; s < nslab; ++s){
    mx = fmaxf(mx, __bfloat162float(maxp[(size_t)s*OUTN_ + j]));
    mn = fminf(mn, __bfloat162float(minp[(size_t)s*OUTN_ + j]));
  }
  float a = ss[o], sh = ss[64 + o];
  float v = (a >= 0.f) ? mx : mn;   // relu(a*z+s) monotone in z, direction sign(a)
  out[j] = fmaxf(fmaf(a, v, sh), 0.f);
}

// ---------------- BN finalize: sum buckets (4-way parallel), scale/shift ----------------

__global__ void finalize_kernel(const float* __restrict__ stb, const float* __restrict__ gamma,
                                const float* __restrict__ beta, float* __restrict__ ss, int C){
  __shared__ float s1s[4][64], s2s[4][64];
  int c = threadIdx.x & 63, part = threadIdx.x >> 6;
  float s1 = 0.f, s2 = 0.f;
  if (c < C)
    for (int k = part; k < NBUCK; k += 4){
      s1 += stb[k*128 + c];
      s2 += stb[k*128 + C + c];
    }
  s1s[part][c] = s1; s2s[part][c] = s2;
  __syncthreads();
  if (part == 0 && c < C){
    s1 = s1s[0][c] + s1s[1][c] + s1s[2][c] + s1s[3][c];
    s2 = s2s[0][c] + s2s[1][c] + s2s[2][c] + s2s[3][c];
    const float invCnt = 1.0f / (float)((size_t)B_*DHW_);
    float mean = s1 * invCnt;
    float var  = s2 * invCnt - mean*mean;
    float a = gamma[c] * rsqrtf(var + EPSV);
    ss[c]     = a;
    ss[C + c] = beta[c] - mean*a;
  }
}

// ---------------- launch ----------------

extern "C" void kernel_launch(void* const* d_in, const int* in_sizes, int n_in,
                              void* d_out, int out_size, void* d_ws, size_t ws_size,
                              hipStream_t stream){
  const float* pc  = (const float*)d_in[0];
  const float* w1  = (const float*)d_in[1];
  const float* b1  = (const float*)d_in[2];
  const float* g1  = (const float*)d_in[3];
  const float* be1 = (const float*)d_in[4];
  const float* w2  = (const float*)d_in[5];
  const float* b2  = (const float*)d_in[6];
  const float* g2  = (const float*)d_in[7];
  const float* be2 = (const float*)d_in[8];
  const float* w3  = (const float*)d_in[9];
  const float* b3  = (const float*)d_in[10];
  const float* g3  = (const float*)d_in[11];
  const float* be3 = (const float*)d_in[12];
  const int N = in_sizes[0] / 6;  // (B=2, 3, N)
  float* out = (float*)d_out;

  char* wsb = (char*)d_ws;
  size_t off = 0;
  auto alloc = [&](size_t bytes)->char*{
    off = (off + 255) & ~(size_t)255;
    char* p = wsb + off; off += bytes; return p;
  };
  float* g0   = (float*)alloc((size_t)B_*DHW_*4);   // 4 MB
  float* wr1  = (float*)alloc(864*4);               // [27k][32o] fp32
  float* wr2  = (float*)alloc(55296*4);             // fp32 (fallback fused12)
  bf16*  wr2b = (bf16*) alloc(55296*2);             // conv2 [oh][tap][iq][o'][j] quarters
  bf16*  wr3b = (bf16*) alloc(110592*2);            // conv3 [oh][ic][tap][iq][o'][j]
  unsigned* minu = (unsigned*)alloc(8*4);
  float* stb  = (float*)alloc((size_t)3*NBUCK*128*4); // bucketed stats, 192 KB
  float* ss   = (float*)alloc(3*128*4);

  constexpr int DCHUNK = 16;
  constexpr int NSLAB  = D_ / DCHUNK;               // 8 grid-slabs
  constexpr int NSLAB2 = NSLAB*2;                   // 16 partial slabs (dsub-split)
  const size_t SX1  = (size_t)B_*DHW_*32*2;         // 64 MiB channel-last bf16
  const size_t SX2  = (size_t)B_*DHW_*64*2;         // 128 MiB channel-last bf16
  const size_t SMM  = (size_t)NSLAB2*OUTN_*2;       // 16.8 MiB per min/max array

  // regionR: x1 (64MiB) aliases minp/maxp (33.6MiB) — disjoint lifetimes
  const size_t prefixEnd = (off + 255) & ~(size_t)255;
  const bool useMfma2 = ws_size >= prefixEnd + SX1 + SX2 + 1024;

  char* regionR = alloc(useMfma2 ? SX1 : 2*SMM);
  bf16* maxp = (bf16*)regionR;
  bf16* minp = (bf16*)(regionR + SMM);
  bf16* x1   = (bf16*)regionR;
  bf16* x2   = (bf16*)alloc(SX2);

  float* st1 = stb;
  float* st2 = stb + (size_t)NBUCK*128;
  float* st3 = stb + (size_t)2*NBUCK*128;

  // prologue (fused): init (minu+stats), prep (zero g0 + minpart + reorders), scatter
  init_kernel<<<64, 256, 0, stream>>>(minu, stb);
  prep_kernel<<<5156, 256, 0, stream>>>(pc, minu, g0, w1, wr1, w2, wr2, wr2b, w3, wr3b, N);
  scatter_kernel<<<(B_*N + 255)/256, 256, 0, stream>>>(pc, minu, g0, N);

  dim3 cgrid(16, 128, 2);                           // (8h-tiles, d, b)
  dim3 m2grid(64, NSLAB, 2);                        // conv2: 1024 blocks x 512 thr (hb|oh)
  dim3 m3grid(64, NSLAB, 2);                        // conv3: 1024 blocks x 512 thr

  if (useMfma2){
    conv1act_kernel<<<cgrid, 256, 0, stream>>>(g0, wr1, b1, x1, st1);
    finalize_kernel<<<1, 256, 0, stream>>>(st1, g1, be1, ss, 32);
    conv2mfma_kernel<DCHUNK><<<m2grid, 512, 0, stream>>>(x1, wr2b, ss, b2, x2, st2);
  } else {
    convstats_kernel<<<cgrid, 256, 0, stream>>>(g0, wr1, b1, st1);
    finalize_kernel<<<1, 256, 0, stream>>>(st1, g1, be1, ss, 32);
    fused12_kernel<<<cgrid, 256, 0, stream>>>(g0, wr1, b1, ss, wr2, b2, x2, st2);
  }
  finalize_kernel<<<1, 256, 0, stream>>>(st2, g2, be2, ss + 128, 64);

  conv3mfma_kernel<DCHUNK><<<m3grid, 512, 0, stream>>>(x2, wr3b, ss + 128, b3, st3, minp, maxp);
  finalize_kernel<<<1, 256, 0, stream>>>(st3, g3, be3, ss + 256, 64);
  bevreduce_kernel<<<(OUTN_ + 255)/256, 256, 0, stream>>>(minp, maxp, ss + 256, out, NSLAB2);
}

// Round 9
// 1445.600 us; speedup vs baseline: 1.7552x; 1.7552x over previous
//
#include <hip/hip_runtime.h>
#include <hip/hip_bf16.h>
#include <float.h>

// LiDAR BEV pipeline (fp32 I/O):
//   voxelize -> conv3d(1->32)+BN+ReLU -> conv3d(32->64)+BN+ReLU -> conv3d(64->64)+BN+ReLU -> max over D
// R22 FAILED (2537us): launch_bounds(512,4) forced VGPR=64 -> total spill (FETCH 2.5GB).
//   The L2-weights mechanism itself never got tested.
// R23: identical to R22 but launch_bounds(512,2): compiler allocates freely (~112-125 VGPR,
//   no spill); with LDS=78,336B the HW grants 2 blocks/CU automatically when VGPR<=128.
//   Wins kept: LDS reads 126->72/phase (weights per-lane from L2-resident wr2b/wr3b ride
//   the parallel vmem pipe), zero weight-DMA barrier drains.
//   Tripwires: VGPR>128 -> occupancy stays 22% (still expect <=R18's 235); FETCH/WRITE
//   inflation -> spill -> revert to R21.

#define VOXEL 0.0625f
#define D_ 128
#define H_ 128
#define W_ 32
#define HW_ (H_*W_)      // 4096
#define DHW_ (D_*H_*W_)  // 524288
#define B_ 2
#define EPSV 1e-5f
#define OUTN_ (B_*64*HW_) // 524288
#define NBUCK 128         // stats buckets

typedef __hip_bfloat16 bf16;
typedef __attribute__((ext_vector_type(8))) short short8;   // 8 bf16
typedef __attribute__((ext_vector_type(4))) short short4v;  // 4 bf16
typedef __attribute__((ext_vector_type(4))) float f32x4;

// order-preserving float->uint key (ascending): neg -> ~bits, nonneg -> bits|signbit
__device__ inline unsigned fminkey(float f){
  unsigned b = __float_as_uint(f);
  return (b & 0x80000000u) ? ~b : (b | 0x80000000u);
}
__device__ inline float fminkey_inv(unsigned u){
  return (u & 0x80000000u) ? __uint_as_float(u & 0x7fffffffu) : __uint_as_float(~u);
}

// ---------------- init: minu + stats buckets ----------------

__global__ void init_kernel(unsigned* __restrict__ minu, float* __restrict__ stb){
  int i = blockIdx.x*blockDim.x + threadIdx.x;
  if (i < 8) minu[i] = 0xFFFFFFFFu;
  for (int k = i; k < 3*NBUCK*128; k += gridDim.x*blockDim.x) stb[k] = 0.f;
}

// ---------------- prep: zero g0 + minpart + all weight reorders (fused) ----------------

__global__ void prep_kernel(const float* __restrict__ pc, unsigned* __restrict__ minu,
                            float* __restrict__ g0,
                            const float* __restrict__ w1, float* __restrict__ wr1,
                            const float* __restrict__ w2, float* __restrict__ wr2,
                            bf16* __restrict__ wr2b,
                            const float* __restrict__ w3, bf16* __restrict__ wr3b,
                            int N){
  const int bid = blockIdx.x;
  const int tid = threadIdx.x;
  if (bid < 4096){                       // zero occupancy grid (1,048,576 floats)
    g0[(size_t)bid*256 + tid] = 0.f;
    return;
  }
  if (bid < 4288){                       // minpart: 192 = 6 rows x 32 x-parts
    int p = bid - 4096;
    int row = p >> 5, xp = p & 31;
    const float* base = pc + (size_t)row * N;
    float m = FLT_MAX;
    for (int j = xp*256 + tid; j < N; j += 8192){
      float v = base[j];
      if (v != v) v = 0.f;               // NaN -> 0, matching reference
      m = fminf(m, v);
    }
    for (int off = 32; off > 0; off >>= 1)
      m = fminf(m, __shfl_xor(m, off, 64));
    __shared__ float red[4];
    int wave = tid >> 6;
    if ((tid & 63) == 0) red[wave] = m;
    __syncthreads();
    if (tid == 0){
      float r = fminf(fminf(red[0], red[1]), fminf(red[2], red[3]));
      atomicMin(&minu[row], fminkey(r));
    }
    return;
  }
  if (bid < 4292){                       // w1 (32,1,27) -> [27tap][32o] fp32
    int idx = (bid - 4288)*256 + tid;
    if (idx < 864){
      int o = idx / 27, k = idx - o*27;
      wr1[k*32 + o] = w1[idx];
    }
    return;
  }
  if (bid < 4508){                       // w2 fp32 [i*27+k][64o] (fallback path)
    int idx = (bid - 4292)*256 + tid;
    if (idx < 55296){
      int o = idx / (32*27);
      int rem = idx - o*(32*27);
      int i = rem / 27, k = rem - i*27;
      wr2[(i*27 + k)*64 + o] = w2[idx];
    }
    return;
  }
  if (bid < 4724){                       // w2 -> [oh][tap][iq][o'][j] bf16 quarters
    int idx = (bid - 4508)*256 + tid;
    if (idx < 55296){
      int o = idx / (32*27);
      int rem = idx - o*(32*27);
      int i = rem / 27, tap = rem - i*27;
      int oh = o >> 5, op = o & 31;
      int iq = i >> 3, j = i & 7;
      wr2b[(((((size_t)oh*27 + tap)*4 + iq)*32 + op) << 3) | j] = __float2bfloat16(w2[idx]);
    }
    return;
  }
  {                                      // w3 -> [oh][ic][tap][iq][o'][j] bf16 quarters
    int idx = (bid - 4724)*256 + tid;
    if (idx < 110592){
      int o = idx / (64*27);
      int rem = idx - o*(64*27);
      int i = rem / 27, tap = rem - i*27;
      int oh = o >> 5, op = o & 31;
      int ic = i >> 5, iq = (i & 31) >> 3, j = i & 7;
      wr3b[(((((size_t)(oh*2 + ic)*27 + tap)*4 + iq)*32 + op) << 3) | j] = __float2bfloat16(w3[idx]);
    }
    return;
  }
}

// ---------------- voxelize scatter ----------------

__global__ void scatter_kernel(const float* __restrict__ pc, const unsigned* __restrict__ minu,
                               float* __restrict__ grid, int N){
  int idx = blockIdx.x*blockDim.x + threadIdx.x;
  if (idx >= B_*N) return;
  int b = idx / N, n = idx - b*N;
  float x = pc[((size_t)b*3 + 0)*N + n];
  float y = pc[((size_t)b*3 + 1)*N + n];
  float z = pc[((size_t)b*3 + 2)*N + n];
  if (x != x) x = 0.f;
  if (y != y) y = 0.f;
  if (z != z) z = 0.f;
  int ix = (int)floorf((x - fminkey_inv(minu[b*3+0])) / VOXEL);
  int iy = (int)floorf((y - fminkey_inv(minu[b*3+1])) / VOXEL);
  int iz = (int)floorf((z - fminkey_inv(minu[b*3+2])) / VOXEL);
  ix = min(max(ix, 0), D_-1);
  iy = min(max(iy, 0), H_-1);
  iz = min(max(iz, 0), W_-1);
  grid[(size_t)b*DHW_ + (size_t)ix*HW_ + iy*W_ + iz] = 1.0f;
}

// ---------------- fp32 conv inner (conv1-class kernels) ----------------

template<int HT, int OPT, int COUT>
__device__ inline void conv_inner(float (*xs)[HT+2][34], float (*wsm)[COUT],
                                  int w, int og, float (*acc)[OPT]){
  #pragma unroll
  for (int kd = 0; kd < 3; ++kd){
    float xr[HT+2][3];
    #pragma unroll
    for (int r = 0; r < HT+2; ++r)
      #pragma unroll
      for (int c = 0; c < 3; ++c)
        xr[r][c] = xs[kd][r][w + c];
    #pragma unroll
    for (int kh = 0; kh < 3; ++kh)
      #pragma unroll
      for (int kw = 0; kw < 3; ++kw){
        const float* wp = &wsm[kd*9 + kh*3 + kw][og*OPT];
        float wv[OPT];
        #pragma unroll
        for (int oo = 0; oo < OPT; ++oo) wv[oo] = wp[oo];
        #pragma unroll
        for (int h = 0; h < HT; ++h){
          float xv = xr[h + kh][kw];
          #pragma unroll
          for (int oo = 0; oo < OPT; ++oo)
            acc[h][oo] = fmaf(xv, wv[oo], acc[h][oo]);
        }
      }
  }
}

// ---------------- conv1 BN stats only (fallback path) ----------------

__global__ __launch_bounds__(256)
void convstats_kernel(const float* __restrict__ X, const float* __restrict__ WR,
                      const float* __restrict__ bias, float* __restrict__ stats){
  const int tid = threadIdx.x;
  const int w   = tid & 31;
  const int og  = tid >> 5;
  const int h0  = blockIdx.x * 8;
  const int d   = blockIdx.y;
  const int b   = blockIdx.z;
  const int bucket = d & (NBUCK - 1);

  __shared__ float xs[3][10][34];
  __shared__ float wsm[27][32];

  float acc[8][4];
  #pragma unroll
  for (int h = 0; h < 8; ++h)
    #pragma unroll
    for (int oo = 0; oo < 4; ++oo) acc[h][oo] = 0.f;

  for (int e = tid; e < 27*32; e += 256)
    ((float*)wsm)[e] = WR[e];
  for (int e = tid; e < 960; e += 256){
    int ds = e / 320; int rem = e - ds*320; int r = rem >> 5; int ww = rem & 31;
    int dd = d + ds - 1, hh = h0 + r - 1;
    float v = 0.f;
    if (dd >= 0 && dd < D_ && hh >= 0 && hh < H_)
      v = X[((size_t)b*D_ + dd)*HW_ + hh*W_ + ww];
    xs[ds][r][ww + 1] = v;
  }
  if (tid < 30){ int ds = tid/10, r = tid - ds*10; xs[ds][r][0] = 0.f; xs[ds][r][33] = 0.f; }
  __syncthreads();
  conv_inner<8, 4, 32>(xs, wsm, w, og, acc);

  #pragma unroll
  for (int oo = 0; oo < 4; ++oo){
    int o = og*4 + oo;
    float bo = bias[o];
    float s1 = 0.f, s2 = 0.f;
    #pragma unroll
    for (int h = 0; h < 8; ++h){
      float y = acc[h][oo] + bo;
      s1 += y;
      s2 = fmaf(y, y, s2);
    }
    for (int m = 16; m > 0; m >>= 1){
      s1 += __shfl_xor(s1, m, 32);
      s2 += __shfl_xor(s2, m, 32);
    }
    if (w == 0){
      atomicAdd(&stats[bucket*128 + o], s1);
      atomicAdd(&stats[bucket*128 + 32 + o], s2);
    }
  }
}

// ---------------- conv1 -> RAW x1 channel-last bf16 [b][d][h][w][32] + BN1 stats ----------------

__global__ __launch_bounds__(256)
void conv1act_kernel(const float* __restrict__ X, const float* __restrict__ WR,
                     const float* __restrict__ bias, bf16* __restrict__ X1,
                     float* __restrict__ stats){
  const int tid = threadIdx.x;
  const int w   = tid & 31;
  const int og  = tid >> 5;
  const int h0  = blockIdx.x * 8;
  const int d   = blockIdx.y;
  const int b   = blockIdx.z;
  const int bucket = d & (NBUCK - 1);

  __shared__ float xs[3][10][34];
  __shared__ float wsm[27][32];

  float acc[8][4];
  #pragma unroll
  for (int h = 0; h < 8; ++h)
    #pragma unroll
    for (int oo = 0; oo < 4; ++oo) acc[h][oo] = 0.f;

  for (int e = tid; e < 27*32; e += 256)
    ((float*)wsm)[e] = WR[e];
  for (int e = tid; e < 960; e += 256){
    int ds = e / 320; int rem = e - ds*320; int r = rem >> 5; int ww = rem & 31;
    int dd = d + ds - 1, hh = h0 + r - 1;
    float v = 0.f;
    if (dd >= 0 && dd < D_ && hh >= 0 && hh < H_)
      v = X[((size_t)b*D_ + dd)*HW_ + hh*W_ + ww];
    xs[ds][r][ww + 1] = v;
  }
  if (tid < 30){ int ds = tid/10, r = tid - ds*10; xs[ds][r][0] = 0.f; xs[ds][r][33] = 0.f; }
  __syncthreads();
  conv_inner<8, 4, 32>(xs, wsm, w, og, acc);

  float bo[4], psum[4], psq[4];
  #pragma unroll
  for (int oo = 0; oo < 4; ++oo){
    bo[oo] = bias[og*4 + oo]; psum[oo] = 0.f; psq[oo] = 0.f;
  }
  #pragma unroll
  for (int h = 0; h < 8; ++h){
    bf16 row[4];
    #pragma unroll
    for (int oo = 0; oo < 4; ++oo){
      float y = acc[h][oo] + bo[oo];
      row[oo] = __float2bfloat16(y);
      psum[oo] += y;
      psq[oo]  = fmaf(y, y, psq[oo]);
    }
    *(short4v*)&X1[((((size_t)b*D_ + d)*H_ + (h0 + h))*W_ + w)*32 + og*4] = *(short4v*)row;
  }
  #pragma unroll
  for (int oo = 0; oo < 4; ++oo){
    float s1 = psum[oo], s2 = psq[oo];
    for (int m = 16; m > 0; m >>= 1){
      s1 += __shfl_xor(s1, m, 32);
      s2 += __shfl_xor(s2, m, 32);
    }
    if (w == 0){
      int o = og*4 + oo;
      atomicAdd(&stats[bucket*128 + o], s1);
      atomicAdd(&stats[bucket*128 + 32 + o], s2);
    }
  }
}

// ---------------- fused12 (fp32 fallback path, writes raw x2 + BN2 stats) ----------------

__global__ __launch_bounds__(256)
void fused12_kernel(const float* __restrict__ G0, const float* __restrict__ WR1,
                    const float* __restrict__ B1, const float* __restrict__ SS1,
                    const float* __restrict__ WR2, const float* __restrict__ B2,
                    bf16* __restrict__ X2, float* __restrict__ stats){
  const int tid = threadIdx.x;
  const int w   = tid & 31;
  const int og  = tid >> 5;
  const int h0  = blockIdx.x * 8;
  const int d   = blockIdx.y;
  const int b   = blockIdx.z;
  const int bucket = d & (NBUCK - 1);

  __shared__ float gs[5][12][34];
  __shared__ float w1s[32][27];
  __shared__ float xs[3][10][34];
  __shared__ float wsm[27][64];

  for (int e = tid; e < 5*12*34; e += 256){
    int ds = e / 408; int rem = e - ds*408; int r = rem / 34; int c = rem - r*34;
    int dd = d - 2 + ds, hh = h0 - 2 + r, ww = c - 1;
    float v = 0.f;
    if (c >= 1 && c <= 32 && dd >= 0 && dd < D_ && hh >= 0 && hh < H_)
      v = G0[((size_t)b*D_ + dd)*HW_ + hh*W_ + ww];
    gs[ds][r][c] = v;
  }
  for (int e = tid; e < 864; e += 256){
    int i = e/27, k = e - 27*i;
    w1s[i][k] = WR1[k*32 + i];
  }

  float acc[8][8];
  #pragma unroll
  for (int h = 0; h < 8; ++h)
    #pragma unroll
    for (int oo = 0; oo < 8; ++oo) acc[h][oo] = 0.f;

  for (int i = 0; i < 32; ++i){
    __syncthreads();
    float a1 = SS1[i];
    float f1 = fmaf(a1, B1[i], SS1[32 + i]);
    for (int e = tid; e < 1020; e += 256){
      int ds = e / 340; int rem = e - ds*340; int r = rem / 34; int c = rem - r*34;
      float v = 0.f;
      int dd = d - 1 + ds, hh = h0 - 1 + r;
      if (c >= 1 && c <= 32 && dd >= 0 && dd < D_ && hh >= 0 && hh < H_){
        float s = 0.f;
        #pragma unroll
        for (int kd = 0; kd < 3; ++kd)
          #pragma unroll
          for (int kh = 0; kh < 3; ++kh)
            #pragma unroll
            for (int kw = 0; kw < 3; ++kw)
              s = fmaf(gs[ds+kd][r+kh][c-1+kw], w1s[i][kd*9+kh*3+kw], s);
        v = fmaxf(fmaf(a1, s, f1), 0.f);
      }
      xs[ds][r][c] = v;
    }
    for (int e = tid; e < 27*64; e += 256)
      ((float*)wsm)[e] = WR2[i*27*64 + e];
    __syncthreads();
    conv_inner<8, 8, 64>(xs, wsm, w, og, acc);
  }

  float bo[8], psum[8], psq[8];
  #pragma unroll
  for (int oo = 0; oo < 8; ++oo){ bo[oo] = B2[og*8 + oo]; psum[oo] = 0.f; psq[oo] = 0.f; }
  #pragma unroll
  for (int h = 0; h < 8; ++h){
    bf16 row[8];
    #pragma unroll
    for (int oo = 0; oo < 8; ++oo){
      float y = acc[h][oo] + bo[oo];
      row[oo] = __float2bfloat16(y);
      psum[oo] += y;
      psq[oo]  = fmaf(y, y, psq[oo]);
    }
    *(short8*)&X2[((((size_t)b*D_ + d)*H_ + (h0 + h))*W_ + w)*64 + og*8] = *(short8*)row;
  }
  #pragma unroll
  for (int oo = 0; oo < 8; ++oo){
    float s1 = psum[oo], s2 = psq[oo];
    for (int m = 16; m > 0; m >>= 1){
      s1 += __shfl_xor(s1, m, 32);
      s2 += __shfl_xor(s2, m, 32);
    }
    if (w == 0){
      atomicAdd(&stats[bucket*128 + og*8 + oo], s1);
      atomicAdd(&stats[bucket*128 + 64 + og*8 + oo], s2);
    }
  }
}

// ---------------- conv2 MFMA (512 thr, o-halved, 2d/wave, kd-dedup, L2 weights) ----------------
// Weights per-lane from L2 (wr2b quarter); LDS = at only (78,336B). launch_bounds(512,2):
// free regalloc; HW grants 2 blocks/CU when VGPR<=128.

template<int DCHUNK>
__global__ __launch_bounds__(512, 2)
void conv2mfma_kernel(const bf16* __restrict__ X1, const bf16* __restrict__ WB,
                      const float* __restrict__ SS1, const float* __restrict__ B2,
                      bf16* __restrict__ X2, float* __restrict__ stats){
  const int tid  = threadIdx.x;
  const int lane = tid & 63;
  const int wv   = tid >> 6;        // 0..7
  const int hrow = wv & 3;
  const int dsub = wv >> 2;
  const int l15  = lane & 15;
  const int quad = lane >> 4;
  const int hb   = blockIdx.x & 31;
  const int oh   = blockIdx.x >> 5;       // o half
  const int h0   = hb * 4;
  const int d0   = blockIdx.y * DCHUNK;
  const int b    = blockIdx.z;
  const int bucket = (hb | ((int)blockIdx.y << 5) | (oh << 6)) & (NBUCK - 1);

  __shared__ __align__(16) bf16 at[6][6][34][32];     // 78,336 B (6 d-slices) — ALL the LDS

  // per-lane weight base in L2: element ((tap*4+quad)*32 + mt*16 + l15)*8
  const bf16* Wl = WB + (size_t)oh*27648 + ((size_t)(quad*32 + l15) << 3);

  // zero the w-halo pad columns (never rewritten)
  for (int e = tid; e < 6*6*2*32; e += 512){
    int ch = e & 31; int side = (e >> 5) & 1; int r = (e >> 6) % 6; int sl = (e >> 6) / 6;
    at[sl][r][side ? 33 : 0][ch] = __float2bfloat16(0.f);
  }

  const int wlane = lane >> 2;
  const int swz   = (((lane >> 2) + 1) >> 1) & 3;
  const int gch   = (lane & 3) ^ swz;

  float sa[8], sb[8];
  #pragma unroll
  for (int j = 0; j < 8; ++j){
    sa[j] = SS1[gch*8 + j];
    sb[j] = SS1[32 + gch*8 + j];
  }

  float br[2][4], psum[2][4], psq[2][4];
  #pragma unroll
  for (int mt = 0; mt < 2; ++mt)
    #pragma unroll
    for (int rg = 0; rg < 4; ++rg){
      br[mt][rg] = B2[oh*32 + mt*16 + quad*4 + rg];
      psum[mt][rg] = 0.f; psq[mt][rg] = 0.f;
    }

  int rsl[5], rr[5];
  #pragma unroll
  for (int jj = 0; jj < 5; ++jj){
    int j = wv + jj*8;
    rsl[jj] = j / 6; rr[jj] = j - rsl[jj]*6;
  }

  short8 xr[10] = {};
  bool rok[5] = {false, false, false, false, false};

  auto stage_load = [&](int dbase){
    #pragma unroll
    for (int jj = 0; jj < 5; ++jj){
      int j = wv + jj*8;                          // wave-uniform
      int dd = dbase - 1 + rsl[jj], hh = h0 - 1 + rr[jj];
      rok[jj] = (j < 36) && dd >= 0 && dd < D_ && hh >= 0 && hh < H_;
      if (rok[jj]){
        const bf16* rowp = X1 + (((size_t)b*D_ + dd)*H_ + hh)*W_*32 + gch*8;
        xr[jj*2+0] = *(const short8*)(rowp + (size_t)wlane*32);
        xr[jj*2+1] = *(const short8*)(rowp + (size_t)(wlane + 16)*32);
      }
    }
  };

  auto stage_flush = [&](){
    // in-place BN1+ReLU transform (pre-barrier)
    #pragma unroll
    for (int jj = 0; jj < 5; ++jj)
      #pragma unroll
      for (int half = 0; half < 2; ++half){
        short8 v = xr[jj*2+half];
        short8 o8 = (short8){0,0,0,0,0,0,0,0};
        if (rok[jj]){
          bf16* pv = (bf16*)&v; bf16* po = (bf16*)&o8;
          #pragma unroll
          for (int j = 0; j < 8; ++j)
            po[j] = __float2bfloat16(fmaxf(fmaf(sa[j], __bfloat162float(pv[j]), sb[j]), 0.f));
        }
        xr[jj*2+half] = o8;
      }
    __syncthreads();                 // all waves done reading at
    #pragma unroll
    for (int jj = 0; jj < 5; ++jj)
      if (wv + jj*8 < 36)            // wave-uniform guard
        #pragma unroll
        for (int half = 0; half < 2; ++half)
          *(short8*)(&at[rsl[jj]][rr[jj]][1 + half*16][0] + (size_t)lane*8) = xr[jj*2+half];
    __syncthreads();                 // publish act writes
  };

  stage_load(d0);

  f32x4 acc[2][2][2];               // [dd][mt][nt]
  #pragma unroll 1
  for (int g = 0; g < DCHUNK/4; ++g){
    const int dbase = d0 + 4*g;
    #pragma unroll
    for (int dd = 0; dd < 2; ++dd)
      #pragma unroll
      for (int mt = 0; mt < 2; ++mt)
        #pragma unroll
        for (int nt = 0; nt < 2; ++nt)
          acc[dd][mt][nt] = (f32x4){0.f, 0.f, 0.f, 0.f};

    stage_flush();
    if (g + 1 < DCHUNK/4) stage_load(dbase + 4);   // in flight across MFMA phase

    #pragma unroll
    for (int kh = 0; kh < 3; ++kh)
      #pragma unroll
      for (int kw = 0; kw < 3; ++kw){
        short8 bfa[4][2];
        #pragma unroll
        for (int sl = 0; sl < 4; ++sl)
          #pragma unroll
          for (int nt = 0; nt < 2; ++nt){
            int W = nt*16 + l15 + kw;
            int pq = (quad ^ ((W >> 1) & 3)) * 8;
            bfa[sl][nt] = *(const short8*)&at[2*dsub + sl][hrow + kh][W][pq];
          }
        #pragma unroll
        for (int kd = 0; kd < 3; ++kd){
          const int tap = (kd*3 + kh)*3 + kw;
          short8 afw[2];
          #pragma unroll
          for (int mt = 0; mt < 2; ++mt)
            afw[mt] = *(const short8*)(Wl + tap*1024 + mt*128);   // L2 read
          #pragma unroll
          for (int dd = 0; dd < 2; ++dd)
            #pragma unroll
            for (int mt = 0; mt < 2; ++mt)
              #pragma unroll
              for (int nt = 0; nt < 2; ++nt)
                acc[dd][mt][nt] = __builtin_amdgcn_mfma_f32_16x16x32_bf16(
                    afw[mt], bfa[dd + kd][nt], acc[dd][mt][nt], 0, 0, 0);
        }
      }

    // epilogue: this wave's 2 d rows
    #pragma unroll
    for (int dd = 0; dd < 2; ++dd){
      const size_t rowbase = (((size_t)b*D_ + (dbase + 2*dsub + dd))*H_ + (h0 + hrow))*W_;
      #pragma unroll
      for (int nt = 0; nt < 2; ++nt){
        const size_t pix = (rowbase + nt*16 + l15)*64;
        #pragma unroll
        for (int mt = 0; mt < 2; ++mt){
          bf16 row[4];
          #pragma unroll
          for (int rg = 0; rg < 4; ++rg){
            float y = acc[dd][mt][nt][rg] + br[mt][rg];
            psum[mt][rg] += y;
            psq[mt][rg]  = fmaf(y, y, psq[mt][rg]);
            row[rg] = __float2bfloat16(y);
          }
          *(short4v*)&X2[pix + oh*32 + mt*16 + quad*4] = *(short4v*)row;
        }
      }
    }
  }

  // BN2 stats
  #pragma unroll
  for (int mt = 0; mt < 2; ++mt)
    #pragma unroll
    for (int rg = 0; rg < 4; ++rg){
      float s1 = psum[mt][rg], s2 = psq[mt][rg];
      #pragma unroll
      for (int m = 1; m < 16; m <<= 1){
        s1 += __shfl_xor(s1, m, 64);
        s2 += __shfl_xor(s2, m, 64);
      }
      if (l15 == 0){
        int o = oh*32 + mt*16 + quad*4 + rg;
        atomicAdd(&stats[bucket*128 + o], s1);
        atomicAdd(&stats[bucket*128 + 64 + o], s2);
      }
    }
}

// ---------------- conv3 MFMA (512 thr, o-halved, M=64/wave, L2 weights) ----------------
// bfr per-lane from L2 (wr3b quarter); LDS = at only (78,336B). 72 LDS reads/phase.

template<int DCHUNK>
__global__ __launch_bounds__(512, 2)
void conv3mfma_kernel(const bf16* __restrict__ X, const bf16* __restrict__ WB,
                      const float* __restrict__ SS2, const float* __restrict__ bias,
                      float* __restrict__ stats,
                      bf16* __restrict__ minp, bf16* __restrict__ maxp){
  const int tid  = threadIdx.x;
  const int lane = tid & 63;
  const int wv   = tid >> 6;
  const int hrow = wv & 3;
  const int dsub = wv >> 2;
  const int l15  = lane & 15;
  const int quad = lane >> 4;
  const int hb   = blockIdx.x & 31;
  const int oh   = blockIdx.x >> 5;       // o half
  const int h0   = hb * 4;
  const int d0   = blockIdx.y * DCHUNK;
  const int b    = blockIdx.z;
  const int bucket = (hb | ((int)blockIdx.y << 5) | (oh << 6)) & (NBUCK - 1);

  __shared__ __align__(16) bf16 at[6][6][34][32];        // 78,336 B — ALL the LDS

  // per-lane weight bases in L2 for both ic quarters
  const bf16* Wl0 = WB + (size_t)(oh*2)*27648 + ((size_t)(quad*32 + l15) << 3);
  const bf16* Wl1 = Wl0 + 27648;

  // zero the w-halo pad columns (never rewritten)
  for (int e = tid; e < 6*6*2*32; e += 512){
    int ch = e & 31; int side = (e >> 5) & 1; int r = (e >> 6) % 6; int sl = (e >> 6) / 6;
    at[sl][r][side ? 33 : 0][ch] = __float2bfloat16(0.f);
  }

  const int wlane = lane >> 2;
  const int swz   = (((lane >> 2) + 1) >> 1) & 3;
  const int gch   = (lane & 3) ^ swz;

  // BN2 scale/shift for this lane's staged channels, both ic halves (ic literal at use sites)
  float sa[2][8], sb[2][8];
  #pragma unroll
  for (int ic = 0; ic < 2; ++ic)
    #pragma unroll
    for (int j = 0; j < 8; ++j){
      sa[ic][j] = SS2[ic*32 + gch*8 + j];
      sb[ic][j] = SS2[64 + ic*32 + gch*8 + j];
    }

  f32x4 acc[4][2];                  // [mh][nt], mh = (mhh<<1)|wh
  float mmx[2][2][4], mmn[2][2][4]; // [wh][nt][rg] (mhh folds into the d-reduction)
  float brg[2];
  #pragma unroll
  for (int nt = 0; nt < 2; ++nt) brg[nt] = bias[oh*32 + nt*16 + l15];
  #pragma unroll
  for (int wh = 0; wh < 2; ++wh)
    #pragma unroll
    for (int nt = 0; nt < 2; ++nt)
      #pragma unroll
      for (int rg = 0; rg < 4; ++rg){ mmx[wh][nt][rg] = -FLT_MAX; mmn[wh][nt][rg] = FLT_MAX; }
  float psum[2] = {0.f,0.f}, psq[2] = {0.f,0.f};

  // 36 rows (6 slices x 6 h-rows); 5 slots/wave (waves 0..3 get 5, 4..7 get 4)
  int rsl[5], rr[5];
  #pragma unroll
  for (int jj = 0; jj < 5; ++jj){
    int j = wv + jj*8;
    rsl[jj] = j / 6; rr[jj] = j - rsl[jj]*6;
  }

  short8 xr[10] = {};
  bool rok[5] = {false, false, false, false, false};

  auto stage_load = [&](int dbase, int ic){
    #pragma unroll
    for (int jj = 0; jj < 5; ++jj){
      int j = wv + jj*8;                          // wave-uniform
      int dd = dbase - 1 + rsl[jj], hh = h0 - 1 + rr[jj];
      rok[jj] = (j < 36) && dd >= 0 && dd < D_ && hh >= 0 && hh < H_;
      if (rok[jj]){
        const bf16* rowp = X + (((size_t)b*D_ + dd)*H_ + hh)*W_*64 + ic*32 + gch*8;
        xr[jj*2+0] = *(const short8*)(rowp + (size_t)wlane*64);
        xr[jj*2+1] = *(const short8*)(rowp + (size_t)(wlane + 16)*64);
      }
    }
  };

  auto stage_flush = [&](int ic){
    // in-place BN2+ReLU transform (pre-barrier: overlaps other waves' MFMAs)
    #pragma unroll
    for (int jj = 0; jj < 5; ++jj)
      #pragma unroll
      for (int half = 0; half < 2; ++half){
        short8 v = xr[jj*2+half];
        short8 o8 = (short8){0,0,0,0,0,0,0,0};
        if (rok[jj]){
          bf16* pv = (bf16*)&v;
          bf16* po = (bf16*)&o8;
          #pragma unroll
          for (int j = 0; j < 8; ++j)
            po[j] = __float2bfloat16(fmaxf(fmaf(sa[ic][j], __bfloat162float(pv[j]), sb[ic][j]), 0.f));
        }
        xr[jj*2+half] = o8;
      }
    __syncthreads();                 // all waves done reading at of prev stage
    #pragma unroll
    for (int jj = 0; jj < 5; ++jj)
      if (wv + jj*8 < 36)            // wave-uniform guard
        #pragma unroll
        for (int half = 0; half < 2; ++half)
          *(short8*)(&at[rsl[jj]][rr[jj]][1 + half*16][0] + (size_t)lane*8) = xr[jj*2+half];
    __syncthreads();                 // publish act writes
  };

  auto do_mfma = [&](const bf16* Wl){
    #pragma unroll
    for (int kh = 0; kh < 3; ++kh)
      #pragma unroll
      for (int kw = 0; kw < 3; ++kw){
        // 8 act vectors: 4 d-slices x 2 w-halves, reused across kd (d-overlap dedup)
        short8 af[4][2];
        #pragma unroll
        for (int sl = 0; sl < 4; ++sl)
          #pragma unroll
          for (int wh = 0; wh < 2; ++wh){
            int W = wh*16 + l15 + kw;
            int pq = (quad ^ ((W >> 1) & 3)) * 8;
            af[sl][wh] = *(const short8*)&at[2*dsub + sl][hrow + kh][W][pq];
          }
        #pragma unroll
        for (int kd = 0; kd < 3; ++kd){
          const int tap = (kd*3 + kh)*3 + kw;
          short8 bfr[2];
          #pragma unroll
          for (int nt = 0; nt < 2; ++nt)
            bfr[nt] = *(const short8*)(Wl + tap*1024 + nt*128);   // L2 read
          #pragma unroll
          for (int mh = 0; mh < 4; ++mh)
            #pragma unroll
            for (int nt = 0; nt < 2; ++nt)
              acc[mh][nt] = __builtin_amdgcn_mfma_f32_16x16x32_bf16(
                  af[(mh >> 1) + kd][mh & 1], bfr[nt], acc[mh][nt], 0, 0, 0);
        }
      }
  };

  // prologue: acts for group 0 ic=0
  stage_load(d0, 0);

  #pragma unroll 1
  for (int g = 0; g < DCHUNK/4; ++g){
    const int dbase = d0 + 4*g;
    #pragma unroll
    for (int mh = 0; mh < 4; ++mh)
      #pragma unroll
      for (int nt = 0; nt < 2; ++nt)
        acc[mh][nt] = (f32x4){0.f, 0.f, 0.f, 0.f};

    // ---- ic = 0 phase ----
    stage_flush(0);
    stage_load(dbase, 1);            // ic1 acts in flight across MFMA
    do_mfma(Wl0);

    // ---- ic = 1 phase ----
    stage_flush(1);
    if (g + 1 < DCHUNK/4) stage_load(dbase + 4, 0);
    do_mfma(Wl1);

    // epilogue: accumulate stats + min/max (mhh folds into d-reduction)
    #pragma unroll
    for (int mh = 0; mh < 4; ++mh){
      const int wh = mh & 1;
      #pragma unroll
      for (int nt = 0; nt < 2; ++nt)
        #pragma unroll
        for (int rg = 0; rg < 4; ++rg){
          float y = acc[mh][nt][rg] + brg[nt];
          psum[nt] += y;
          psq[nt]  = fmaf(y, y, psq[nt]);
          mmx[wh][nt][rg] = fmaxf(mmx[wh][nt][rg], y);
          mmn[wh][nt][rg] = fminf(mmn[wh][nt][rg], y);
        }
    }
  }

  // BN3 stats: lanes {l15, +16, +32, +48} share o = oh*32 + nt*16 + l15
  #pragma unroll
  for (int nt = 0; nt < 2; ++nt){
    float s1 = psum[nt], s2 = psq[nt];
    s1 += __shfl_xor(s1, 16, 64);  s2 += __shfl_xor(s2, 16, 64);
    s1 += __shfl_xor(s1, 32, 64);  s2 += __shfl_xor(s2, 32, 64);
    if (quad == 0){
      int o = oh*32 + nt*16 + l15;
      atomicAdd(&stats[bucket*128 + o], s1);
      atomicAdd(&stats[bucket*128 + 64 + o], s2);
    }
  }

  const size_t slab_off = (size_t)((int)blockIdx.y*2 + dsub) * OUTN_;
  const int h = h0 + hrow;
  #pragma unroll
  for (int wh = 0; wh < 2; ++wh)
    #pragma unroll
    for (int nt = 0; nt < 2; ++nt){
      int o = oh*32 + nt*16 + l15;
      #pragma unroll
      for (int rg = 0; rg < 4; ++rg){
        int w = wh*16 + quad*4 + rg;
        size_t idx = slab_off + ((size_t)(b*64 + o))*HW_ + h*W_ + w;
        maxp[idx] = __float2bfloat16(mmx[wh][nt][rg]);
        minp[idx] = __float2bfloat16(mmn[wh][nt][rg]);
      }
    }
}

// ---------------- final: reduce slabs, apply BN3+ReLU via monotonicity ----------------

__global__ void bevreduce_kernel(const bf16* __restrict__ minp, const bf16* __restrict__ maxp,
                                 const float* __restrict__ ss, float* __restrict__ out, int nslab){
  int j = blockIdx.x*blockDim.x + threadIdx.x;
  if (j >= OUTN_) return;
  int o = (j >> 12) & 63;
  float mx = -FLT_MAX, mn = FLT_MAX;
  for (int s = 0; s < nslab; ++s){
    mx = fmaxf(mx, __bfloat162float(maxp[(size_t)s*OUTN_ + j]));
    mn = fminf(mn, __bfloat162float(minp[(size_t)s*OUTN_ + j]));
  }
  float a = ss[o], sh = ss[64 + o];
  float v = (a >= 0.f) ? mx : mn;   // relu(a*z+s) monotone in z, direction sign(a)
  out[j] = fmaxf(fmaf(a, v, sh), 0.f);
}

// ---------------- BN finalize: sum buckets (4-way parallel), scale/shift ----------------

__global__ void finalize_kernel(const float* __restrict__ stb, const float* __restrict__ gamma,
                                const float* __restrict__ beta, float* __restrict__ ss, int C){
  __shared__ float s1s[4][64], s2s[4][64];
  int c = threadIdx.x & 63, part = threadIdx.x >> 6;
  float s1 = 0.f, s2 = 0.f;
  if (c < C)
    for (int k = part; k < NBUCK; k += 4){
      s1 += stb[k*128 + c];
      s2 += stb[k*128 + C + c];
    }
  s1s[part][c] = s1; s2s[part][c] = s2;
  __syncthreads();
  if (part == 0 && c < C){
    s1 = s1s[0][c] + s1s[1][c] + s1s[2][c] + s1s[3][c];
    s2 = s2s[0][c] + s2s[1][c] + s2s[2][c] + s2s[3][c];
    const float invCnt = 1.0f / (float)((size_t)B_*DHW_);
    float mean = s1 * invCnt;
    float var  = s2 * invCnt - mean*mean;
    float a = gamma[c] * rsqrtf(var + EPSV);
    ss[c]     = a;
    ss[C + c] = beta[c] - mean*a;
  }
}

// ---------------- launch ----------------

extern "C" void kernel_launch(void* const* d_in, const int* in_sizes, int n_in,
                              void* d_out, int out_size, void* d_ws, size_t ws_size,
                              hipStream_t stream){
  const float* pc  = (const float*)d_in[0];
  const float* w1  = (const float*)d_in[1];
  const float* b1  = (const float*)d_in[2];
  const float* g1  = (const float*)d_in[3];
  const float* be1 = (const float*)d_in[4];
  const float* w2  = (const float*)d_in[5];
  const float* b2  = (const float*)d_in[6];
  const float* g2  = (const float*)d_in[7];
  const float* be2 = (const float*)d_in[8];
  const float* w3  = (const float*)d_in[9];
  const float* b3  = (const float*)d_in[10];
  const float* g3  = (const float*)d_in[11];
  const float* be3 = (const float*)d_in[12];
  const int N = in_sizes[0] / 6;  // (B=2, 3, N)
  float* out = (float*)d_out;

  char* wsb = (char*)d_ws;
  size_t off = 0;
  auto alloc = [&](size_t bytes)->char*{
    off = (off + 255) & ~(size_t)255;
    char* p = wsb + off; off += bytes; return p;
  };
  float* g0   = (float*)alloc((size_t)B_*DHW_*4);   // 4 MB
  float* wr1  = (float*)alloc(864*4);               // [27k][32o] fp32
  float* wr2  = (float*)alloc(55296*4);             // fp32 (fallback fused12)
  bf16*  wr2b = (bf16*) alloc(55296*2);             // conv2 [oh][tap][iq][o'][j] quarters
  bf16*  wr3b = (bf16*) alloc(110592*2);            // conv3 [oh][ic][tap][iq][o'][j]
  unsigned* minu = (unsigned*)alloc(8*4);
  float* stb  = (float*)alloc((size_t)3*NBUCK*128*4); // bucketed stats, 192 KB
  float* ss   = (float*)alloc(3*128*4);

  constexpr int DCHUNK = 16;
  constexpr int NSLAB  = D_ / DCHUNK;               // 8 grid-slabs
  constexpr int NSLAB2 = NSLAB*2;                   // 16 partial slabs (dsub-split)
  const size_t SX1  = (size_t)B_*DHW_*32*2;         // 64 MiB channel-last bf16
  const size_t SX2  = (size_t)B_*DHW_*64*2;         // 128 MiB channel-last bf16
  const size_t SMM  = (size_t)NSLAB2*OUTN_*2;       // 16.8 MiB per min/max array

  // regionR: x1 (64MiB) aliases minp/maxp (33.6MiB) — disjoint lifetimes
  const size_t prefixEnd = (off + 255) & ~(size_t)255;
  const bool useMfma2 = ws_size >= prefixEnd + SX1 + SX2 + 1024;

  char* regionR = alloc(useMfma2 ? SX1 : 2*SMM);
  bf16* maxp = (bf16*)regionR;
  bf16* minp = (bf16*)(regionR + SMM);
  bf16* x1   = (bf16*)regionR;
  bf16* x2   = (bf16*)alloc(SX2);

  float* st1 = stb;
  float* st2 = stb + (size_t)NBUCK*128;
  float* st3 = stb + (size_t)2*NBUCK*128;

  // prologue (fused): init (minu+stats), prep (zero g0 + minpart + reorders), scatter
  init_kernel<<<64, 256, 0, stream>>>(minu, stb);
  prep_kernel<<<5156, 256, 0, stream>>>(pc, minu, g0, w1, wr1, w2, wr2, wr2b, w3, wr3b, N);
  scatter_kernel<<<(B_*N + 255)/256, 256, 0, stream>>>(pc, minu, g0, N);

  dim3 cgrid(16, 128, 2);                           // (8h-tiles, d, b)
  dim3 m2grid(64, NSLAB, 2);                        // conv2: 1024 blocks x 512 thr (hb|oh)
  dim3 m3grid(64, NSLAB, 2);                        // conv3: 1024 blocks x 512 thr

  if (useMfma2){
    conv1act_kernel<<<cgrid, 256, 0, stream>>>(g0, wr1, b1, x1, st1);
    finalize_kernel<<<1, 256, 0, stream>>>(st1, g1, be1, ss, 32);
    conv2mfma_kernel<DCHUNK><<<m2grid, 512, 0, stream>>>(x1, wr2b, ss, b2, x2, st2);
  } else {
    convstats_kernel<<<cgrid, 256, 0, stream>>>(g0, wr1, b1, st1);
    finalize_kernel<<<1, 256, 0, stream>>>(st1, g1, be1, ss, 32);
    fused12_kernel<<<cgrid, 256, 0, stream>>>(g0, wr1, b1, ss, wr2, b2, x2, st2);
  }
  finalize_kernel<<<1, 256, 0, stream>>>(st2, g2, be2, ss + 128, 64);

  conv3mfma_kernel<DCHUNK><<<m3grid, 512, 0, stream>>>(x2, wr3b, ss + 128, b3, st3, minp, maxp);
  finalize_kernel<<<1, 256, 0, stream>>>(st3, g3, be3, ss + 256, 64);
  bevreduce_kernel<<<(OUTN_ + 255)/256, 256, 0, stream>>>(minp, maxp, ss + 256, out, NSLAB2);
}

// Round 10
// 501.102 us; speedup vs baseline: 5.0636x; 2.8848x over previous
//
#include <hip/hip_runtime.h>
#include <hip/hip_bf16.h>
#include <float.h>

// LiDAR BEV pipeline (fp32 I/O):
//   voxelize -> conv3d(1->32)+BN+ReLU -> conv3d(32->64)+BN+ReLU -> conv3d(64->64)+BN+ReLU -> max over D
// R22/R23 FAILED (2537/1445us): L2-weights branch. R23's lesson: with LDS=78KB the
//   allocator caps VGPR at 128 to chase 2 blocks/CU (despite launch_bounds(512,2) allowing
//   256) -> spill (FETCH 2GB). Small LDS INVITES the occupancy-for-registers trade.
// R24: revert to known-good R21 config: conv3 = R18 kd-dedup structure (streamed wsm
//   quarter in LDS, 133,632B total -> 1 block/CU pinned, 112 VGPR, no spill); conv2 =
//   rolling-ring; fused init/prep prologue. Measured family: 502-516us (conv3 235-253
//   cross-run noise). Eight structural probes confirm this is the decomposition's optimum:
//   bigger tiles LDS-capacity-blocked, pair-ic accs spill, L2-weights spill.

#define VOXEL 0.0625f
#define D_ 128
#define H_ 128
#define W_ 32
#define HW_ (H_*W_)      // 4096
#define DHW_ (D_*H_*W_)  // 524288
#define B_ 2
#define EPSV 1e-5f
#define OUTN_ (B_*64*HW_) // 524288
#define NBUCK 128         // stats buckets

typedef __hip_bfloat16 bf16;
typedef __attribute__((ext_vector_type(8))) short short8;   // 8 bf16
typedef __attribute__((ext_vector_type(4))) short short4v;  // 4 bf16
typedef __attribute__((ext_vector_type(4))) float f32x4;

__device__ inline void gl_lds16(const void* g, void* l){
  // async global->LDS, 16B per lane; LDS dest = base + lane*16 (wave-uniform base)
  __builtin_amdgcn_global_load_lds(
      (const __attribute__((address_space(1))) unsigned int*)g,
      (__attribute__((address_space(3))) unsigned int*)l, 16, 0, 0);
}

// order-preserving float->uint key (ascending): neg -> ~bits, nonneg -> bits|signbit
__device__ inline unsigned fminkey(float f){
  unsigned b = __float_as_uint(f);
  return (b & 0x80000000u) ? ~b : (b | 0x80000000u);
}
__device__ inline float fminkey_inv(unsigned u){
  return (u & 0x80000000u) ? __uint_as_float(u & 0x7fffffffu) : __uint_as_float(~u);
}

// ---------------- init: minu + stats buckets ----------------

__global__ void init_kernel(unsigned* __restrict__ minu, float* __restrict__ stb){
  int i = blockIdx.x*blockDim.x + threadIdx.x;
  if (i < 8) minu[i] = 0xFFFFFFFFu;
  for (int k = i; k < 3*NBUCK*128; k += gridDim.x*blockDim.x) stb[k] = 0.f;
}

// ---------------- prep: zero g0 + minpart + all weight reorders (fused) ----------------

__global__ void prep_kernel(const float* __restrict__ pc, unsigned* __restrict__ minu,
                            float* __restrict__ g0,
                            const float* __restrict__ w1, float* __restrict__ wr1,
                            const float* __restrict__ w2, float* __restrict__ wr2,
                            bf16* __restrict__ wr2b,
                            const float* __restrict__ w3, bf16* __restrict__ wr3b,
                            int N){
  const int bid = blockIdx.x;
  const int tid = threadIdx.x;
  if (bid < 4096){                       // zero occupancy grid (1,048,576 floats)
    g0[(size_t)bid*256 + tid] = 0.f;
    return;
  }
  if (bid < 4288){                       // minpart: 192 = 6 rows x 32 x-parts
    int p = bid - 4096;
    int row = p >> 5, xp = p & 31;
    const float* base = pc + (size_t)row * N;
    float m = FLT_MAX;
    for (int j = xp*256 + tid; j < N; j += 8192){
      float v = base[j];
      if (v != v) v = 0.f;               // NaN -> 0, matching reference
      m = fminf(m, v);
    }
    for (int off = 32; off > 0; off >>= 1)
      m = fminf(m, __shfl_xor(m, off, 64));
    __shared__ float red[4];
    int wave = tid >> 6;
    if ((tid & 63) == 0) red[wave] = m;
    __syncthreads();
    if (tid == 0){
      float r = fminf(fminf(red[0], red[1]), fminf(red[2], red[3]));
      atomicMin(&minu[row], fminkey(r));
    }
    return;
  }
  if (bid < 4292){                       // w1 (32,1,27) -> [27tap][32o] fp32
    int idx = (bid - 4288)*256 + tid;
    if (idx < 864){
      int o = idx / 27, k = idx - o*27;
      wr1[k*32 + o] = w1[idx];
    }
    return;
  }
  if (bid < 4508){                       // w2 fp32 [i*27+k][64o] (fallback path)
    int idx = (bid - 4292)*256 + tid;
    if (idx < 55296){
      int o = idx / (32*27);
      int rem = idx - o*(32*27);
      int i = rem / 27, k = rem - i*27;
      wr2[(i*27 + k)*64 + o] = w2[idx];
    }
    return;
  }
  if (bid < 4724){                       // w2 -> [oh][tap][iq][o'][j] bf16 quarters
    int idx = (bid - 4508)*256 + tid;
    if (idx < 55296){
      int o = idx / (32*27);
      int rem = idx - o*(32*27);
      int i = rem / 27, tap = rem - i*27;
      int oh = o >> 5, op = o & 31;
      int iq = i >> 3, j = i & 7;
      wr2b[(((((size_t)oh*27 + tap)*4 + iq)*32 + op) << 3) | j] = __float2bfloat16(w2[idx]);
    }
    return;
  }
  {                                      // w3 -> [oh][ic][tap][iq][o'][j] bf16 quarters
    int idx = (bid - 4724)*256 + tid;
    if (idx < 110592){
      int o = idx / (64*27);
      int rem = idx - o*(64*27);
      int i = rem / 27, tap = rem - i*27;
      int oh = o >> 5, op = o & 31;
      int ic = i >> 5, iq = (i & 31) >> 3, j = i & 7;
      wr3b[(((((size_t)(oh*2 + ic)*27 + tap)*4 + iq)*32 + op) << 3) | j] = __float2bfloat16(w3[idx]);
    }
    return;
  }
}

// ---------------- voxelize scatter ----------------

__global__ void scatter_kernel(const float* __restrict__ pc, const unsigned* __restrict__ minu,
                               float* __restrict__ grid, int N){
  int idx = blockIdx.x*blockDim.x + threadIdx.x;
  if (idx >= B_*N) return;
  int b = idx / N, n = idx - b*N;
  float x = pc[((size_t)b*3 + 0)*N + n];
  float y = pc[((size_t)b*3 + 1)*N + n];
  float z = pc[((size_t)b*3 + 2)*N + n];
  if (x != x) x = 0.f;
  if (y != y) y = 0.f;
  if (z != z) z = 0.f;
  int ix = (int)floorf((x - fminkey_inv(minu[b*3+0])) / VOXEL);
  int iy = (int)floorf((y - fminkey_inv(minu[b*3+1])) / VOXEL);
  int iz = (int)floorf((z - fminkey_inv(minu[b*3+2])) / VOXEL);
  ix = min(max(ix, 0), D_-1);
  iy = min(max(iy, 0), H_-1);
  iz = min(max(iz, 0), W_-1);
  grid[(size_t)b*DHW_ + (size_t)ix*HW_ + iy*W_ + iz] = 1.0f;
}

// ---------------- fp32 conv inner (conv1-class kernels) ----------------

template<int HT, int OPT, int COUT>
__device__ inline void conv_inner(float (*xs)[HT+2][34], float (*wsm)[COUT],
                                  int w, int og, float (*acc)[OPT]){
  #pragma unroll
  for (int kd = 0; kd < 3; ++kd){
    float xr[HT+2][3];
    #pragma unroll
    for (int r = 0; r < HT+2; ++r)
      #pragma unroll
      for (int c = 0; c < 3; ++c)
        xr[r][c] = xs[kd][r][w + c];
    #pragma unroll
    for (int kh = 0; kh < 3; ++kh)
      #pragma unroll
      for (int kw = 0; kw < 3; ++kw){
        const float* wp = &wsm[kd*9 + kh*3 + kw][og*OPT];
        float wv[OPT];
        #pragma unroll
        for (int oo = 0; oo < OPT; ++oo) wv[oo] = wp[oo];
        #pragma unroll
        for (int h = 0; h < HT; ++h){
          float xv = xr[h + kh][kw];
          #pragma unroll
          for (int oo = 0; oo < OPT; ++oo)
            acc[h][oo] = fmaf(xv, wv[oo], acc[h][oo]);
        }
      }
  }
}

// ---------------- conv1 BN stats only (fallback path) ----------------

__global__ __launch_bounds__(256)
void convstats_kernel(const float* __restrict__ X, const float* __restrict__ WR,
                      const float* __restrict__ bias, float* __restrict__ stats){
  const int tid = threadIdx.x;
  const int w   = tid & 31;
  const int og  = tid >> 5;
  const int h0  = blockIdx.x * 8;
  const int d   = blockIdx.y;
  const int b   = blockIdx.z;
  const int bucket = d & (NBUCK - 1);

  __shared__ float xs[3][10][34];
  __shared__ float wsm[27][32];

  float acc[8][4];
  #pragma unroll
  for (int h = 0; h < 8; ++h)
    #pragma unroll
    for (int oo = 0; oo < 4; ++oo) acc[h][oo] = 0.f;

  for (int e = tid; e < 27*32; e += 256)
    ((float*)wsm)[e] = WR[e];
  for (int e = tid; e < 960; e += 256){
    int ds = e / 320; int rem = e - ds*320; int r = rem >> 5; int ww = rem & 31;
    int dd = d + ds - 1, hh = h0 + r - 1;
    float v = 0.f;
    if (dd >= 0 && dd < D_ && hh >= 0 && hh < H_)
      v = X[((size_t)b*D_ + dd)*HW_ + hh*W_ + ww];
    xs[ds][r][ww + 1] = v;
  }
  if (tid < 30){ int ds = tid/10, r = tid - ds*10; xs[ds][r][0] = 0.f; xs[ds][r][33] = 0.f; }
  __syncthreads();
  conv_inner<8, 4, 32>(xs, wsm, w, og, acc);

  #pragma unroll
  for (int oo = 0; oo < 4; ++oo){
    int o = og*4 + oo;
    float bo = bias[o];
    float s1 = 0.f, s2 = 0.f;
    #pragma unroll
    for (int h = 0; h < 8; ++h){
      float y = acc[h][oo] + bo;
      s1 += y;
      s2 = fmaf(y, y, s2);
    }
    for (int m = 16; m > 0; m >>= 1){
      s1 += __shfl_xor(s1, m, 32);
      s2 += __shfl_xor(s2, m, 32);
    }
    if (w == 0){
      atomicAdd(&stats[bucket*128 + o], s1);
      atomicAdd(&stats[bucket*128 + 32 + o], s2);
    }
  }
}

// ---------------- conv1 -> RAW x1 channel-last bf16 [b][d][h][w][32] + BN1 stats ----------------

__global__ __launch_bounds__(256)
void conv1act_kernel(const float* __restrict__ X, const float* __restrict__ WR,
                     const float* __restrict__ bias, bf16* __restrict__ X1,
                     float* __restrict__ stats){
  const int tid = threadIdx.x;
  const int w   = tid & 31;
  const int og  = tid >> 5;
  const int h0  = blockIdx.x * 8;
  const int d   = blockIdx.y;
  const int b   = blockIdx.z;
  const int bucket = d & (NBUCK - 1);

  __shared__ float xs[3][10][34];
  __shared__ float wsm[27][32];

  float acc[8][4];
  #pragma unroll
  for (int h = 0; h < 8; ++h)
    #pragma unroll
    for (int oo = 0; oo < 4; ++oo) acc[h][oo] = 0.f;

  for (int e = tid; e < 27*32; e += 256)
    ((float*)wsm)[e] = WR[e];
  for (int e = tid; e < 960; e += 256){
    int ds = e / 320; int rem = e - ds*320; int r = rem >> 5; int ww = rem & 31;
    int dd = d + ds - 1, hh = h0 + r - 1;
    float v = 0.f;
    if (dd >= 0 && dd < D_ && hh >= 0 && hh < H_)
      v = X[((size_t)b*D_ + dd)*HW_ + hh*W_ + ww];
    xs[ds][r][ww + 1] = v;
  }
  if (tid < 30){ int ds = tid/10, r = tid - ds*10; xs[ds][r][0] = 0.f; xs[ds][r][33] = 0.f; }
  __syncthreads();
  conv_inner<8, 4, 32>(xs, wsm, w, og, acc);

  float bo[4], psum[4], psq[4];
  #pragma unroll
  for (int oo = 0; oo < 4; ++oo){
    bo[oo] = bias[og*4 + oo]; psum[oo] = 0.f; psq[oo] = 0.f;
  }
  #pragma unroll
  for (int h = 0; h < 8; ++h){
    bf16 row[4];
    #pragma unroll
    for (int oo = 0; oo < 4; ++oo){
      float y = acc[h][oo] + bo[oo];
      row[oo] = __float2bfloat16(y);
      psum[oo] += y;
      psq[oo]  = fmaf(y, y, psq[oo]);
    }
    *(short4v*)&X1[((((size_t)b*D_ + d)*H_ + (h0 + h))*W_ + w)*32 + og*4] = *(short4v*)row;
  }
  #pragma unroll
  for (int oo = 0; oo < 4; ++oo){
    float s1 = psum[oo], s2 = psq[oo];
    for (int m = 16; m > 0; m >>= 1){
      s1 += __shfl_xor(s1, m, 32);
      s2 += __shfl_xor(s2, m, 32);
    }
    if (w == 0){
      int o = og*4 + oo;
      atomicAdd(&stats[bucket*128 + o], s1);
      atomicAdd(&stats[bucket*128 + 32 + o], s2);
    }
  }
}

// ---------------- fused12 (fp32 fallback path, writes raw x2 + BN2 stats) ----------------

__global__ __launch_bounds__(256)
void fused12_kernel(const float* __restrict__ G0, const float* __restrict__ WR1,
                    const float* __restrict__ B1, const float* __restrict__ SS1,
                    const float* __restrict__ WR2, const float* __restrict__ B2,
                    bf16* __restrict__ X2, float* __restrict__ stats){
  const int tid = threadIdx.x;
  const int w   = tid & 31;
  const int og  = tid >> 5;
  const int h0  = blockIdx.x * 8;
  const int d   = blockIdx.y;
  const int b   = blockIdx.z;
  const int bucket = d & (NBUCK - 1);

  __shared__ float gs[5][12][34];
  __shared__ float w1s[32][27];
  __shared__ float xs[3][10][34];
  __shared__ float wsm[27][64];

  for (int e = tid; e < 5*12*34; e += 256){
    int ds = e / 408; int rem = e - ds*408; int r = rem / 34; int c = rem - r*34;
    int dd = d - 2 + ds, hh = h0 - 2 + r, ww = c - 1;
    float v = 0.f;
    if (c >= 1 && c <= 32 && dd >= 0 && dd < D_ && hh >= 0 && hh < H_)
      v = G0[((size_t)b*D_ + dd)*HW_ + hh*W_ + ww];
    gs[ds][r][c] = v;
  }
  for (int e = tid; e < 864; e += 256){
    int i = e/27, k = e - 27*i;
    w1s[i][k] = WR1[k*32 + i];
  }

  float acc[8][8];
  #pragma unroll
  for (int h = 0; h < 8; ++h)
    #pragma unroll
    for (int oo = 0; oo < 8; ++oo) acc[h][oo] = 0.f;

  for (int i = 0; i < 32; ++i){
    __syncthreads();
    float a1 = SS1[i];
    float f1 = fmaf(a1, B1[i], SS1[32 + i]);
    for (int e = tid; e < 1020; e += 256){
      int ds = e / 340; int rem = e - ds*340; int r = rem / 34; int c = rem - r*34;
      float v = 0.f;
      int dd = d - 1 + ds, hh = h0 - 1 + r;
      if (c >= 1 && c <= 32 && dd >= 0 && dd < D_ && hh >= 0 && hh < H_){
        float s = 0.f;
        #pragma unroll
        for (int kd = 0; kd < 3; ++kd)
          #pragma unroll
          for (int kh = 0; kh < 3; ++kh)
            #pragma unroll
            for (int kw = 0; kw < 3; ++kw)
              s = fmaf(gs[ds+kd][r+kh][c-1+kw], w1s[i][kd*9+kh*3+kw], s);
        v = fmaxf(fmaf(a1, s, f1), 0.f);
      }
      xs[ds][r][c] = v;
    }
    for (int e = tid; e < 27*64; e += 256)
      ((float*)wsm)[e] = WR2[i*27*64 + e];
    __syncthreads();
    conv_inner<8, 8, 64>(xs, wsm, w, og, acc);
  }

  float bo[8], psum[8], psq[8];
  #pragma unroll
  for (int oo = 0; oo < 8; ++oo){ bo[oo] = B2[og*8 + oo]; psum[oo] = 0.f; psq[oo] = 0.f; }
  #pragma unroll
  for (int h = 0; h < 8; ++h){
    bf16 row[8];
    #pragma unroll
    for (int oo = 0; oo < 8; ++oo){
      float y = acc[h][oo] + bo[oo];
      row[oo] = __float2bfloat16(y);
      psum[oo] += y;
      psq[oo]  = fmaf(y, y, psq[oo]);
    }
    *(short8*)&X2[((((size_t)b*D_ + d)*H_ + (h0 + h))*W_ + w)*64 + og*8] = *(short8*)row;
  }
  #pragma unroll
  for (int oo = 0; oo < 8; ++oo){
    float s1 = psum[oo], s2 = psq[oo];
    for (int m = 16; m > 0; m >>= 1){
      s1 += __shfl_xor(s1, m, 32);
      s2 += __shfl_xor(s2, m, 32);
    }
    if (w == 0){
      atomicAdd(&stats[bucket*128 + og*8 + oo], s1);
      atomicAdd(&stats[bucket*128 + 64 + og*8 + oo], s2);
    }
  }
}

// ---------------- conv2 MFMA (512 thr, o-halved, 2d/wave, kd-dedup + rolling ring) ----------------
// 8-slice rolling ring. g0 staged full (36 rows, phys 0..5); g1/g2/g3 stage only the 4
// NEW slices (24 rows; phys {6,7,0,1} / {2,3,4,5} / {6,7,0,1}). mfma ring base alternates
// 0/4/0/4. Weights (32-o quarter, 55,296B) loaded once. LDS 104,448 + 55,296 = 159,744B.

template<int DCHUNK>
__global__ __launch_bounds__(512, 2)
void conv2mfma_kernel(const bf16* __restrict__ X1, const bf16* __restrict__ WB,
                      const float* __restrict__ SS1, const float* __restrict__ B2,
                      bf16* __restrict__ X2, float* __restrict__ stats){
  const int tid  = threadIdx.x;
  const int lane = tid & 63;
  const int wv   = tid >> 6;        // 0..7
  const int hrow = wv & 3;
  const int dsub = wv >> 2;
  const int l15  = lane & 15;
  const int quad = lane >> 4;
  const int hb   = blockIdx.x & 31;
  const int oh   = blockIdx.x >> 5;       // o half
  const int h0   = hb * 4;
  const int d0   = blockIdx.y * DCHUNK;
  const int b    = blockIdx.z;
  const int bucket = (hb | ((int)blockIdx.y << 5) | (oh << 6)) & (NBUCK - 1);

  __shared__ __align__(16) bf16 at[8][6][34][32];     // 104,448 B rolling ring
  __shared__ __align__(16) bf16 wsm[27][4][32][8];    // 55,296 B (one 32-o quarter)

  {
    bf16* wl = &wsm[0][0][0][0];
    const bf16* wg = WB + (size_t)oh*27648;
    for (int c = wv; c < 54; c += 8)
      gl_lds16(wg + (size_t)c*512 + lane*8, wl + (size_t)c*512);
  }
  for (int e = tid; e < 8*6*2*32; e += 512){
    int ch = e & 31; int side = (e >> 5) & 1; int r = (e >> 6) % 6; int sl = (e >> 6) / 6;
    at[sl][r][side ? 33 : 0][ch] = __float2bfloat16(0.f);
  }

  const int wlane = lane >> 2;
  const int swz   = (((lane >> 2) + 1) >> 1) & 3;
  const int gch   = (lane & 3) ^ swz;

  float sa[8], sb[8];
  #pragma unroll
  for (int j = 0; j < 8; ++j){
    sa[j] = SS1[gch*8 + j];
    sb[j] = SS1[32 + gch*8 + j];
  }

  float br[2][4], psum[2][4], psq[2][4];
  #pragma unroll
  for (int mt = 0; mt < 2; ++mt)
    #pragma unroll
    for (int rg = 0; rg < 4; ++rg){
      br[mt][rg] = B2[oh*32 + mt*16 + quad*4 + rg];
      psum[mt][rg] = 0.f; psq[mt][rg] = 0.f;
    }

  // full-stage mapping: 36 rows, 5 slots; delta: 24 rows, 3 slots
  int rsl[5], rr[5], dsl[3], dr2[3];
  #pragma unroll
  for (int jj = 0; jj < 5; ++jj){
    int j = wv + jj*8;
    rsl[jj] = j / 6; rr[jj] = j - rsl[jj]*6;
  }
  #pragma unroll
  for (int jj = 0; jj < 3; ++jj){
    int j = wv + jj*8;
    dsl[jj] = j / 6; dr2[jj] = j - dsl[jj]*6;
  }

  short8 xr[10] = {};
  bool rok[5] = {false, false, false, false, false};

  auto load_full = [&](int dbase){
    #pragma unroll
    for (int jj = 0; jj < 5; ++jj){
      int j = wv + jj*8;
      int dd = dbase - 1 + rsl[jj], hh = h0 - 1 + rr[jj];
      rok[jj] = (j < 36) && dd >= 0 && dd < D_ && hh >= 0 && hh < H_;
      if (rok[jj]){
        const bf16* rowp = X1 + (((size_t)b*D_ + dd)*H_ + hh)*W_*32 + gch*8;
        xr[jj*2+0] = *(const short8*)(rowp + (size_t)wlane*32);
        xr[jj*2+1] = *(const short8*)(rowp + (size_t)(wlane + 16)*32);
      }
    }
  };
  auto load_delta = [&](int dbase){      // new slices dd = dbase+1 .. dbase+4
    #pragma unroll
    for (int jj = 0; jj < 3; ++jj){
      int dd = dbase + 1 + dsl[jj], hh = h0 - 1 + dr2[jj];
      rok[jj] = dd >= 0 && dd < D_ && hh >= 0 && hh < H_;
      if (rok[jj]){
        const bf16* rowp = X1 + (((size_t)b*D_ + dd)*H_ + hh)*W_*32 + gch*8;
        xr[jj*2+0] = *(const short8*)(rowp + (size_t)wlane*32);
        xr[jj*2+1] = *(const short8*)(rowp + (size_t)(wlane + 16)*32);
      }
    }
  };

  auto flush_full = [&](){
    #pragma unroll
    for (int jj = 0; jj < 5; ++jj)
      #pragma unroll
      for (int half = 0; half < 2; ++half){
        short8 v = xr[jj*2+half];
        short8 o8 = (short8){0,0,0,0,0,0,0,0};
        if (rok[jj]){
          bf16* pv = (bf16*)&v; bf16* po = (bf16*)&o8;
          #pragma unroll
          for (int j = 0; j < 8; ++j)
            po[j] = __float2bfloat16(fmaxf(fmaf(sa[j], __bfloat162float(pv[j]), sb[j]), 0.f));
        }
        xr[jj*2+half] = o8;
      }
    __syncthreads();
    #pragma unroll
    for (int jj = 0; jj < 5; ++jj)
      if (wv + jj*8 < 36)
        #pragma unroll
        for (int half = 0; half < 2; ++half)
          *(short8*)(&at[rsl[jj]][rr[jj]][1 + half*16][0] + (size_t)lane*8) = xr[jj*2+half];
    __syncthreads();
  };
  auto flush_delta = [&](int pb){        // pb = 6 or 2 (literal); phys = (pb+dsl)&7
    #pragma unroll
    for (int jj = 0; jj < 3; ++jj)
      #pragma unroll
      for (int half = 0; half < 2; ++half){
        short8 v = xr[jj*2+half];
        short8 o8 = (short8){0,0,0,0,0,0,0,0};
        if (rok[jj]){
          bf16* pv = (bf16*)&v; bf16* po = (bf16*)&o8;
          #pragma unroll
          for (int j = 0; j < 8; ++j)
            po[j] = __float2bfloat16(fmaxf(fmaf(sa[j], __bfloat162float(pv[j]), sb[j]), 0.f));
        }
        xr[jj*2+half] = o8;
      }
    __syncthreads();
    #pragma unroll
    for (int jj = 0; jj < 3; ++jj){
      int ph = (pb + dsl[jj]) & 7;
      #pragma unroll
      for (int half = 0; half < 2; ++half)
        *(short8*)(&at[ph][dr2[jj]][1 + half*16][0] + (size_t)lane*8) = xr[jj*2+half];
    }
    __syncthreads();
  };

  f32x4 acc[2][2][2];               // [dd][mt][nt]
  auto do_group = [&](int gb, int dbase){
    #pragma unroll
    for (int dd = 0; dd < 2; ++dd)
      #pragma unroll
      for (int mt = 0; mt < 2; ++mt)
        #pragma unroll
        for (int nt = 0; nt < 2; ++nt)
          acc[dd][mt][nt] = (f32x4){0.f, 0.f, 0.f, 0.f};
    #pragma unroll
    for (int kh = 0; kh < 3; ++kh)
      #pragma unroll
      for (int kw = 0; kw < 3; ++kw){
        short8 bfa[4][2];
        #pragma unroll
        for (int sl = 0; sl < 4; ++sl)
          #pragma unroll
          for (int nt = 0; nt < 2; ++nt){
            int W = nt*16 + l15 + kw;
            int pq = (quad ^ ((W >> 1) & 3)) * 8;
            bfa[sl][nt] = *(const short8*)&at[(gb + 2*dsub + sl) & 7][hrow + kh][W][pq];
          }
        #pragma unroll
        for (int kd = 0; kd < 3; ++kd){
          const int tap = (kd*3 + kh)*3 + kw;
          short8 afw[2];
          #pragma unroll
          for (int mt = 0; mt < 2; ++mt)
            afw[mt] = *(const short8*)&wsm[tap][quad][mt*16 + l15][0];
          #pragma unroll
          for (int dd = 0; dd < 2; ++dd)
            #pragma unroll
            for (int mt = 0; mt < 2; ++mt)
              #pragma unroll
              for (int nt = 0; nt < 2; ++nt)
                acc[dd][mt][nt] = __builtin_amdgcn_mfma_f32_16x16x32_bf16(
                    afw[mt], bfa[dd + kd][nt], acc[dd][mt][nt], 0, 0, 0);
        }
      }
    // epilogue: this wave's 2 d rows
    #pragma unroll
    for (int dd = 0; dd < 2; ++dd){
      const size_t rowbase = (((size_t)b*D_ + (dbase + 2*dsub + dd))*H_ + (h0 + hrow))*W_;
      #pragma unroll
      for (int nt = 0; nt < 2; ++nt){
        const size_t pix = (rowbase + nt*16 + l15)*64;
        #pragma unroll
        for (int mt = 0; mt < 2; ++mt){
          bf16 row[4];
          #pragma unroll
          for (int rg = 0; rg < 4; ++rg){
            float y = acc[dd][mt][nt][rg] + br[mt][rg];
            psum[mt][rg] += y;
            psq[mt][rg]  = fmaf(y, y, psq[mt][rg]);
            row[rg] = __float2bfloat16(y);
          }
          *(short4v*)&X2[pix + oh*32 + mt*16 + quad*4] = *(short4v*)row;
        }
      }
    }
  };

  load_full(d0);
  // g0
  flush_full();           load_delta(d0 + 4);   do_group(0, d0);
  // g1
  flush_delta(6);         load_delta(d0 + 8);   do_group(4, d0 + 4);
  // g2
  flush_delta(2);         load_delta(d0 + 12);  do_group(0, d0 + 8);
  // g3
  flush_delta(6);                               do_group(4, d0 + 12);

  // BN2 stats
  #pragma unroll
  for (int mt = 0; mt < 2; ++mt)
    #pragma unroll
    for (int rg = 0; rg < 4; ++rg){
      float s1 = psum[mt][rg], s2 = psq[mt][rg];
      #pragma unroll
      for (int m = 1; m < 16; m <<= 1){
        s1 += __shfl_xor(s1, m, 64);
        s2 += __shfl_xor(s2, m, 64);
      }
      if (l15 == 0){
        int o = oh*32 + mt*16 + quad*4 + rg;
        atomicAdd(&stats[bucket*128 + o], s1);
        atomicAdd(&stats[bucket*128 + 64 + o], s2);
      }
    }
}

// ---------------- conv3 MFMA (512 thr, o-halved, M=64/wave): R18 structure (no spill) ----------------
// Waves = 4 hrow x 2 dsub; wave computes {dbase+2dsub, +1} x 32w x 32o. (kh,kw) outer,
// 8 af vectors (4 slices x 2 wh) loaded once, kd inner reuses them -> per phase 126
// ds_read_b128 (af 72 + bfr 54). wsm = one (oh,ic) quarter (55,296 B), re-staged from L2
// each stage between the flush barriers. Single acc set (112 VGPR, no scratch).

template<int DCHUNK>
__global__ __launch_bounds__(512, 2)
void conv3mfma_kernel(const bf16* __restrict__ X, const bf16* __restrict__ WB,
                      const float* __restrict__ SS2, const float* __restrict__ bias,
                      float* __restrict__ stats,
                      bf16* __restrict__ minp, bf16* __restrict__ maxp){
  const int tid  = threadIdx.x;
  const int lane = tid & 63;
  const int wv   = tid >> 6;
  const int hrow = wv & 3;
  const int dsub = wv >> 2;
  const int l15  = lane & 15;
  const int quad = lane >> 4;
  const int hb   = blockIdx.x & 31;
  const int oh   = blockIdx.x >> 5;       // o half
  const int h0   = hb * 4;
  const int d0   = blockIdx.y * DCHUNK;
  const int b    = blockIdx.z;
  const int bucket = (hb | ((int)blockIdx.y << 5) | (oh << 6)) & (NBUCK - 1);

  __shared__ __align__(16) bf16 at[6][6][34][32];        // 78,336 B (6 d-slices)
  __shared__ __align__(16) bf16 wsm[27][4][32][8];       // 55,296 B (one (oh,ic) quarter)

  // zero the w-halo pad columns (never rewritten)
  for (int e = tid; e < 6*6*2*32; e += 512){
    int ch = e & 31; int side = (e >> 5) & 1; int r = (e >> 6) % 6; int sl = (e >> 6) / 6;
    at[sl][r][side ? 33 : 0][ch] = __float2bfloat16(0.f);
  }

  const int wlane = lane >> 2;
  const int swz   = (((lane >> 2) + 1) >> 1) & 3;
  const int gch   = (lane & 3) ^ swz;

  // BN2 scale/shift for this lane's staged channels, both ic halves (ic literal at use sites)
  float sa[2][8], sb[2][8];
  #pragma unroll
  for (int ic = 0; ic < 2; ++ic)
    #pragma unroll
    for (int j = 0; j < 8; ++j){
      sa[ic][j] = SS2[ic*32 + gch*8 + j];
      sb[ic][j] = SS2[64 + ic*32 + gch*8 + j];
    }

  f32x4 acc[4][2];                  // [mh][nt], mh = (mhh<<1)|wh
  float mmx[2][2][4], mmn[2][2][4]; // [wh][nt][rg] (mhh folds into the d-reduction)
  float brg[2];
  #pragma unroll
  for (int nt = 0; nt < 2; ++nt) brg[nt] = bias[oh*32 + nt*16 + l15];
  #pragma unroll
  for (int wh = 0; wh < 2; ++wh)
    #pragma unroll
    for (int nt = 0; nt < 2; ++nt)
      #pragma unroll
      for (int rg = 0; rg < 4; ++rg){ mmx[wh][nt][rg] = -FLT_MAX; mmn[wh][nt][rg] = FLT_MAX; }
  float psum[2] = {0.f,0.f}, psq[2] = {0.f,0.f};

  // 36 rows (6 slices x 6 h-rows); 5 slots/wave (waves 0..3 get 5, 4..7 get 4)
  int rsl[5], rr[5];
  #pragma unroll
  for (int jj = 0; jj < 5; ++jj){
    int j = wv + jj*8;
    rsl[jj] = j / 6; rr[jj] = j - rsl[jj]*6;
  }

  short8 xr[10] = {};
  bool rok[5] = {false, false, false, false, false};

  auto stage_load = [&](int dbase, int ic){
    #pragma unroll
    for (int jj = 0; jj < 5; ++jj){
      int j = wv + jj*8;                          // wave-uniform
      int dd = dbase - 1 + rsl[jj], hh = h0 - 1 + rr[jj];
      rok[jj] = (j < 36) && dd >= 0 && dd < D_ && hh >= 0 && hh < H_;
      if (rok[jj]){
        const bf16* rowp = X + (((size_t)b*D_ + dd)*H_ + hh)*W_*64 + ic*32 + gch*8;
        xr[jj*2+0] = *(const short8*)(rowp + (size_t)wlane*64);
        xr[jj*2+1] = *(const short8*)(rowp + (size_t)(wlane + 16)*64);
      }
    }
  };

  auto load_w = [&](int ic){
    bf16* wl = &wsm[0][0][0][0];
    const bf16* wg = WB + (size_t)(oh*2 + ic)*27648;   // quarter stride
    for (int c = wv; c < 54; c += 8)
      gl_lds16(wg + (size_t)c*512 + lane*8, wl + (size_t)c*512);
  };

  auto stage_flush = [&](int ic, bool loadW){
    // in-place BN2+ReLU transform (pre-barrier: overlaps other waves' MFMAs)
    #pragma unroll
    for (int jj = 0; jj < 5; ++jj)
      #pragma unroll
      for (int half = 0; half < 2; ++half){
        short8 v = xr[jj*2+half];
        short8 o8 = (short8){0,0,0,0,0,0,0,0};
        if (rok[jj]){
          bf16* pv = (bf16*)&v;
          bf16* po = (bf16*)&o8;
          #pragma unroll
          for (int j = 0; j < 8; ++j)
            po[j] = __float2bfloat16(fmaxf(fmaf(sa[ic][j], __bfloat162float(pv[j]), sb[ic][j]), 0.f));
        }
        xr[jj*2+half] = o8;
      }
    __syncthreads();                 // all waves done reading at & wsm of prev stage
    #pragma unroll
    for (int jj = 0; jj < 5; ++jj)
      if (wv + jj*8 < 36)            // wave-uniform guard
        #pragma unroll
        for (int half = 0; half < 2; ++half)
          *(short8*)(&at[rsl[jj]][rr[jj]][1 + half*16][0] + (size_t)lane*8) = xr[jj*2+half];
    if (loadW) load_w(ic);
    __syncthreads();                 // drains weight gl_lds16 + act writes
  };

  auto do_mfma = [&](){
    #pragma unroll
    for (int kh = 0; kh < 3; ++kh)
      #pragma unroll
      for (int kw = 0; kw < 3; ++kw){
        // 8 act vectors: 4 d-slices x 2 w-halves, reused across kd (d-overlap dedup)
        short8 af[4][2];
        #pragma unroll
        for (int sl = 0; sl < 4; ++sl)
          #pragma unroll
          for (int wh = 0; wh < 2; ++wh){
            int W = wh*16 + l15 + kw;
            int pq = (quad ^ ((W >> 1) & 3)) * 8;
            af[sl][wh] = *(const short8*)&at[2*dsub + sl][hrow + kh][W][pq];
          }
        #pragma unroll
        for (int kd = 0; kd < 3; ++kd){
          const int tap = (kd*3 + kh)*3 + kw;
          short8 bfr[2];
          #pragma unroll
          for (int nt = 0; nt < 2; ++nt)
            bfr[nt] = *(const short8*)&wsm[tap][quad][nt*16 + l15][0];
          #pragma unroll
          for (int mh = 0; mh < 4; ++mh)
            #pragma unroll
            for (int nt = 0; nt < 2; ++nt)
              acc[mh][nt] = __builtin_amdgcn_mfma_f32_16x16x32_bf16(
                  af[(mh >> 1) + kd][mh & 1], bfr[nt], acc[mh][nt], 0, 0, 0);
        }
      }
  };

  // prologue: weights quarter (oh, ic=0) + acts for group 0 ic=0
  load_w(0);
  stage_load(d0, 0);

  #pragma unroll 1
  for (int g = 0; g < DCHUNK/4; ++g){
    const int dbase = d0 + 4*g;
    #pragma unroll
    for (int mh = 0; mh < 4; ++mh)
      #pragma unroll
      for (int nt = 0; nt < 2; ++nt)
        acc[mh][nt] = (f32x4){0.f, 0.f, 0.f, 0.f};

    // ---- ic = 0 phase ----
    stage_flush(0, g > 0);           // prologue already loaded ic0 weights for g=0
    stage_load(dbase, 1);            // ic1 acts in flight across MFMA
    do_mfma();

    // ---- ic = 1 phase ----
    stage_flush(1, true);
    if (g + 1 < DCHUNK/4) stage_load(dbase + 4, 0);
    do_mfma();

    // epilogue: accumulate stats + min/max (mhh folds into d-reduction)
    #pragma unroll
    for (int mh = 0; mh < 4; ++mh){
      const int wh = mh & 1;
      #pragma unroll
      for (int nt = 0; nt < 2; ++nt)
        #pragma unroll
        for (int rg = 0; rg < 4; ++rg){
          float y = acc[mh][nt][rg] + brg[nt];
          psum[nt] += y;
          psq[nt]  = fmaf(y, y, psq[nt]);
          mmx[wh][nt][rg] = fmaxf(mmx[wh][nt][rg], y);
          mmn[wh][nt][rg] = fminf(mmn[wh][nt][rg], y);
        }
    }
  }

  // BN3 stats: lanes {l15, +16, +32, +48} share o = oh*32 + nt*16 + l15
  #pragma unroll
  for (int nt = 0; nt < 2; ++nt){
    float s1 = psum[nt], s2 = psq[nt];
    s1 += __shfl_xor(s1, 16, 64);  s2 += __shfl_xor(s2, 16, 64);
    s1 += __shfl_xor(s1, 32, 64);  s2 += __shfl_xor(s2, 32, 64);
    if (quad == 0){
      int o = oh*32 + nt*16 + l15;
      atomicAdd(&stats[bucket*128 + o], s1);
      atomicAdd(&stats[bucket*128 + 64 + o], s2);
    }
  }

  const size_t slab_off = (size_t)((int)blockIdx.y*2 + dsub) * OUTN_;
  const int h = h0 + hrow;
  #pragma unroll
  for (int wh = 0; wh < 2; ++wh)
    #pragma unroll
    for (int nt = 0; nt < 2; ++nt){
      int o = oh*32 + nt*16 + l15;
      #pragma unroll
      for (int rg = 0; rg < 4; ++rg){
        int w = wh*16 + quad*4 + rg;
        size_t idx = slab_off + ((size_t)(b*64 + o))*HW_ + h*W_ + w;
        maxp[idx] = __float2bfloat16(mmx[wh][nt][rg]);
        minp[idx] = __float2bfloat16(mmn[wh][nt][rg]);
      }
    }
}

// ---------------- final: reduce slabs, apply BN3+ReLU via monotonicity ----------------

__global__ void bevreduce_kernel(const bf16* __restrict__ minp, const bf16* __restrict__ maxp,
                                 const float* __restrict__ ss, float* __restrict__ out, int nslab){
  int j = blockIdx.x*blockDim.x + threadIdx.x;
  if (j >= OUTN_) return;
  int o = (j >> 12) & 63;
  float mx = -FLT_MAX, mn = FLT_MAX;
  for (int s = 0; s < nslab; ++s){
    mx = fmaxf(mx, __bfloat162float(maxp[(size_t)s*OUTN_ + j]));
    mn = fminf(mn, __bfloat162float(minp[(size_t)s*OUTN_ + j]));
  }
  float a = ss[o], sh = ss[64 + o];
  float v = (a >= 0.f) ? mx : mn;   // relu(a*z+s) monotone in z, direction sign(a)
  out[j] = fmaxf(fmaf(a, v, sh), 0.f);
}

// ---------------- BN finalize: sum buckets (4-way parallel), scale/shift ----------------

__global__ void finalize_kernel(const float* __restrict__ stb, const float* __restrict__ gamma,
                                const float* __restrict__ beta, float* __restrict__ ss, int C){
  __shared__ float s1s[4][64], s2s[4][64];
  int c = threadIdx.x & 63, part = threadIdx.x >> 6;
  float s1 = 0.f, s2 = 0.f;
  if (c < C)
    for (int k = part; k < NBUCK; k += 4){
      s1 += stb[k*128 + c];
      s2 += stb[k*128 + C + c];
    }
  s1s[part][c] = s1; s2s[part][c] = s2;
  __syncthreads();
  if (part == 0 && c < C){
    s1 = s1s[0][c] + s1s[1][c] + s1s[2][c] + s1s[3][c];
    s2 = s2s[0][c] + s2s[1][c] + s2s[2][c] + s2s[3][c];
    const float invCnt = 1.0f / (float)((size_t)B_*DHW_);
    float mean = s1 * invCnt;
    float var  = s2 * invCnt - mean*mean;
    float a = gamma[c] * rsqrtf(var + EPSV);
    ss[c]     = a;
    ss[C + c] = beta[c] - mean*a;
  }
}

// ---------------- launch ----------------

extern "C" void kernel_launch(void* const* d_in, const int* in_sizes, int n_in,
                              void* d_out, int out_size, void* d_ws, size_t ws_size,
                              hipStream_t stream){
  const float* pc  = (const float*)d_in[0];
  const float* w1  = (const float*)d_in[1];
  const float* b1  = (const float*)d_in[2];
  const float* g1  = (const float*)d_in[3];
  const float* be1 = (const float*)d_in[4];
  const float* w2  = (const float*)d_in[5];
  const float* b2  = (const float*)d_in[6];
  const float* g2  = (const float*)d_in[7];
  const float* be2 = (const float*)d_in[8];
  const float* w3  = (const float*)d_in[9];
  const float* b3  = (const float*)d_in[10];
  const float* g3  = (const float*)d_in[11];
  const float* be3 = (const float*)d_in[12];
  const int N = in_sizes[0] / 6;  // (B=2, 3, N)
  float* out = (float*)d_out;

  char* wsb = (char*)d_ws;
  size_t off = 0;
  auto alloc = [&](size_t bytes)->char*{
    off = (off + 255) & ~(size_t)255;
    char* p = wsb + off; off += bytes; return p;
  };
  float* g0   = (float*)alloc((size_t)B_*DHW_*4);   // 4 MB
  float* wr1  = (float*)alloc(864*4);               // [27k][32o] fp32
  float* wr2  = (float*)alloc(55296*4);             // fp32 (fallback fused12)
  bf16*  wr2b = (bf16*) alloc(55296*2);             // conv2 [oh][tap][iq][o'][j] quarters
  bf16*  wr3b = (bf16*) alloc(110592*2);            // conv3 [oh][ic][tap][iq][o'][j]
  unsigned* minu = (unsigned*)alloc(8*4);
  float* stb  = (float*)alloc((size_t)3*NBUCK*128*4); // bucketed stats, 192 KB
  float* ss   = (float*)alloc(3*128*4);

  constexpr int DCHUNK = 16;
  constexpr int NSLAB  = D_ / DCHUNK;               // 8 grid-slabs
  constexpr int NSLAB2 = NSLAB*2;                   // 16 partial slabs (dsub-split)
  const size_t SX1  = (size_t)B_*DHW_*32*2;         // 64 MiB channel-last bf16
  const size_t SX2  = (size_t)B_*DHW_*64*2;         // 128 MiB channel-last bf16
  const size_t SMM  = (size_t)NSLAB2*OUTN_*2;       // 16.8 MiB per min/max array

  // regionR: x1 (64MiB) aliases minp/maxp (33.6MiB) — disjoint lifetimes
  const size_t prefixEnd = (off + 255) & ~(size_t)255;
  const bool useMfma2 = ws_size >= prefixEnd + SX1 + SX2 + 1024;

  char* regionR = alloc(useMfma2 ? SX1 : 2*SMM);
  bf16* maxp = (bf16*)regionR;
  bf16* minp = (bf16*)(regionR + SMM);
  bf16* x1   = (bf16*)regionR;
  bf16* x2   = (bf16*)alloc(SX2);

  float* st1 = stb;
  float* st2 = stb + (size_t)NBUCK*128;
  float* st3 = stb + (size_t)2*NBUCK*128;

  // prologue (fused): init (minu+stats), prep (zero g0 + minpart + reorders), scatter
  init_kernel<<<64, 256, 0, stream>>>(minu, stb);
  prep_kernel<<<5156, 256, 0, stream>>>(pc, minu, g0, w1, wr1, w2, wr2, wr2b, w3, wr3b, N);
  scatter_kernel<<<(B_*N + 255)/256, 256, 0, stream>>>(pc, minu, g0, N);

  dim3 cgrid(16, 128, 2);                           // (8h-tiles, d, b)
  dim3 m2grid(64, NSLAB, 2);                        // conv2: 1024 blocks x 512 thr (hb|oh)
  dim3 m3grid(64, NSLAB, 2);                        // conv3: 1024 blocks x 512 thr

  if (useMfma2){
    conv1act_kernel<<<cgrid, 256, 0, stream>>>(g0, wr1, b1, x1, st1);
    finalize_kernel<<<1, 256, 0, stream>>>(st1, g1, be1, ss, 32);
    conv2mfma_kernel<DCHUNK><<<m2grid, 512, 0, stream>>>(x1, wr2b, ss, b2, x2, st2);
  } else {
    convstats_kernel<<<cgrid, 256, 0, stream>>>(g0, wr1, b1, st1);
    finalize_kernel<<<1, 256, 0, stream>>>(st1, g1, be1, ss, 32);
    fused12_kernel<<<cgrid, 256, 0, stream>>>(g0, wr1, b1, ss, wr2, b2, x2, st2);
  }
  finalize_kernel<<<1, 256, 0, stream>>>(st2, g2, be2, ss + 128, 64);

  conv3mfma_kernel<DCHUNK><<<m3grid, 512, 0, stream>>>(x2, wr3b, ss + 128, b3, st3, minp, maxp);
  finalize_kernel<<<1, 256, 0, stream>>>(st3, g3, be3, ss + 256, 64);
  bevreduce_kernel<<<(OUTN_ + 255)/256, 256, 0, stream>>>(minp, maxp, ss + 256, out, NSLAB2);
}